// Round 1
// baseline (6235.703 us; speedup 1.0000x reference)
//
#include <hip/hip_runtime.h>
#include <hip/hip_bf16.h>
#include <math.h>

#define BB 8
#define SS 512
#define DDIM 512
#define HH 8
#define DKK 64
#define DFFV 2048
#define NLAYER 6
#define EPSV 1e-5f

// ---------------- embed + positional encoding ----------------
__global__ __launch_bounds__(256) void embed_pe_kernel(
    const int* __restrict__ idx, const float* __restrict__ emb,
    float* __restrict__ x) {
  int t = blockIdx.x * blockDim.x + threadIdx.x;  // over B*S*D
  if (t >= BB * SS * DDIM) return;
  int d = t & (DDIM - 1);
  int bs = t >> 9;         // / DDIM
  int s = bs & (SS - 1);
  int tok = idx[bs];
  int i2 = d & ~1;
  float ang = (float)s * powf(10000.0f, -((float)i2) / (float)DDIM);
  float pe = (d & 1) ? cosf(ang) : sinf(ang);
  x[t] = emb[tok * DDIM + d] + pe;
}

// ---------------- generic tiled fp32 GEMM with bias (+optional relu) -------
// C[m,n] = sum_k A[m*K+k] * Bw[(n>>lgDN)*sH + k*sK + (n&(DN-1))] + bias[n]
template <int RELU>
__global__ __launch_bounds__(256) void gemm_bias_kernel(
    const float* __restrict__ A, const float* __restrict__ Bw,
    const float* __restrict__ bias, float* __restrict__ C,
    int M, int Nn, int K, int sH, int sK, int lgDN) {
  __shared__ float As[64][17];   // [mm][kk], pad 17 to spread banks
  __shared__ float Bs[16][64];   // [kk][nn]
  int bm = blockIdx.y * 64, bn = blockIdx.x * 64;
  int tid = threadIdx.x;
  int tm = (tid >> 4) * 4, tn = (tid & 15) * 4;
  float acc[4][4] = {};
  int dnm1 = (1 << lgDN) - 1;
  for (int k0 = 0; k0 < K; k0 += 16) {
#pragma unroll
    for (int i = 0; i < 4; i++) {
      int e = tid + i * 256;           // 0..1023
      int mm = e >> 4, kk = e & 15;
      As[mm][kk] = A[(bm + mm) * K + k0 + kk];
      int kk2 = e >> 6, nn = e & 63;
      int n = bn + nn;
      Bs[kk2][nn] = Bw[(n >> lgDN) * sH + (k0 + kk2) * sK + (n & dnm1)];
    }
    __syncthreads();
#pragma unroll
    for (int kk = 0; kk < 16; kk++) {
      float a[4], b[4];
#pragma unroll
      for (int i = 0; i < 4; i++) a[i] = As[tm + i][kk];
#pragma unroll
      for (int j = 0; j < 4; j++) b[j] = Bs[kk][tn + j];
#pragma unroll
      for (int i = 0; i < 4; i++)
#pragma unroll
        for (int j = 0; j < 4; j++) acc[i][j] += a[i] * b[j];
    }
    __syncthreads();
  }
#pragma unroll
  for (int i = 0; i < 4; i++) {
    int m = bm + tm + i;
#pragma unroll
    for (int j = 0; j < 4; j++) {
      int n = bn + tn + j;
      float v = acc[i][j] + bias[n];
      if (RELU) v = fmaxf(v, 0.0f);
      C[m * Nn + n] = v;
    }
  }
}

// ---------------- attention (scores materialized in LDS) ----------------
// q,k,v: [B,S,H,DK]; mask: [B,S,S] additive; out: [B,S,H*DV]
// grid: (S/16, H, B); 256 threads
__global__ __launch_bounds__(256) void attn_kernel(
    const float* __restrict__ q, const float* __restrict__ k,
    const float* __restrict__ v, const float* __restrict__ mask,
    float* __restrict__ out) {
  __shared__ float sc[16][512];     // 32 KB
  __shared__ float Klds[64][65];    // padded
  __shared__ float Qlds[16][68];    // padded
  int qc = blockIdx.x, h = blockIdx.y, b = blockIdx.z;
  int q0 = qc * 16;
  int tid = threadIdx.x;

  // stage Q tile (16x64)
#pragma unroll
  for (int i = 0; i < 4; i++) {
    int e = tid + i * 256;
    int r = e >> 6, t = e & 63;
    Qlds[r][t] = q[(((b * SS) + q0 + r) * HH + h) * DKK + t];
  }

  int qr = tid >> 4;          // 0..15
  int kj0 = (tid & 15) * 4;   // 0..60

  for (int c = 0; c < 8; c++) {
    __syncthreads();  // Klds free (also covers Qlds staging at c==0)
#pragma unroll
    for (int i = 0; i < 16; i++) {
      int e = tid + i * 256;   // 0..4095
      int r = e >> 6, t = e & 63;
      Klds[r][t] = k[(((b * SS) + c * 64 + r) * HH + h) * DKK + t];
    }
    __syncthreads();
    float accs[4] = {0.f, 0.f, 0.f, 0.f};
    for (int t = 0; t < 64; t++) {
      float qv = Qlds[qr][t];
#pragma unroll
      for (int j = 0; j < 4; j++) accs[j] += qv * Klds[kj0 + j][t];
    }
#pragma unroll
    for (int j = 0; j < 4; j++) {
      int s_idx = c * 64 + kj0 + j;
      sc[qr][s_idx] =
          accs[j] * 0.125f + mask[((b * SS) + q0 + qr) * SS + s_idx];
    }
  }
  __syncthreads();

  // softmax: wave w handles rows w, w+4, w+8, w+12
  int wid = tid >> 6, lane = tid & 63;
  for (int rr = wid; rr < 16; rr += 4) {
    float vals[8];
    float m = -1e30f;
#pragma unroll
    for (int i = 0; i < 8; i++) {
      vals[i] = sc[rr][lane + 64 * i];
      m = fmaxf(m, vals[i]);
    }
#pragma unroll
    for (int off = 32; off > 0; off >>= 1) m = fmaxf(m, __shfl_xor(m, off));
    float ssum = 0.f;
#pragma unroll
    for (int i = 0; i < 8; i++) {
      vals[i] = __expf(vals[i] - m);
      ssum += vals[i];
    }
#pragma unroll
    for (int off = 32; off > 0; off >>= 1) ssum += __shfl_xor(ssum, off);
    float inv = 1.0f / ssum;
#pragma unroll
    for (int i = 0; i < 8; i++) sc[rr][lane + 64 * i] = vals[i] * inv;
  }
  __syncthreads();

  // PV: thread owns col t = tid&63, rows r0+4j
  int t = tid & 63;
  int r0 = tid >> 6;  // 0..3
  float acc[4] = {0.f, 0.f, 0.f, 0.f};
  for (int s = 0; s < SS; s++) {
    float vv = v[(((b * SS) + s) * HH + h) * DKK + t];
#pragma unroll
    for (int j = 0; j < 4; j++) acc[j] += sc[r0 + 4 * j][s] * vv;
  }
#pragma unroll
  for (int j = 0; j < 4; j++) {
    int r = r0 + 4 * j;
    out[(((b * SS) + q0 + r) * HH + h) * DKK + t] = acc[j];
  }
}

// ---------------- residual add + LayerNorm (in place on x) ----------------
__global__ __launch_bounds__(128) void add_ln_kernel(
    float* __restrict__ x, const float* __restrict__ y,
    const float* __restrict__ g, const float* __restrict__ bta) {
  int row = blockIdx.x;
  int tid = threadIdx.x;
  __shared__ float red[2];
  int base = row * DDIM + tid * 4;
  float4 xv = *reinterpret_cast<const float4*>(x + base);
  float4 yv = *reinterpret_cast<const float4*>(y + base);
  float v0 = xv.x + yv.x, v1 = xv.y + yv.y, v2 = xv.z + yv.z, v3 = xv.w + yv.w;
  float s = v0 + v1 + v2 + v3;
#pragma unroll
  for (int off = 32; off > 0; off >>= 1) s += __shfl_xor(s, off);
  int lane = tid & 63, wid = tid >> 6;
  if (lane == 0) red[wid] = s;
  __syncthreads();
  float mean = (red[0] + red[1]) * (1.0f / DDIM);
  float d0 = v0 - mean, d1 = v1 - mean, d2 = v2 - mean, d3 = v3 - mean;
  float t2 = d0 * d0 + d1 * d1 + d2 * d2 + d3 * d3;
#pragma unroll
  for (int off = 32; off > 0; off >>= 1) t2 += __shfl_xor(t2, off);
  __syncthreads();  // everyone has read red before overwrite
  if (lane == 0) red[wid] = t2;
  __syncthreads();
  float var = (red[0] + red[1]) * (1.0f / DDIM);
  float rs = rsqrtf(var + EPSV);
  int c = tid * 4;
  float4 gv = *reinterpret_cast<const float4*>(g + c);
  float4 bv = *reinterpret_cast<const float4*>(bta + c);
  float4 o;
  o.x = d0 * rs * gv.x + bv.x;
  o.y = d1 * rs * gv.y + bv.y;
  o.z = d2 * rs * gv.z + bv.z;
  o.w = d3 * rs * gv.w + bv.w;
  *reinterpret_cast<float4*>(x + base) = o;
}

// ---------------- orchestration ----------------
extern "C" void kernel_launch(void* const* d_in, const int* in_sizes, int n_in,
                              void* d_out, int out_size, void* d_ws,
                              size_t ws_size, hipStream_t stream) {
  const int* dec = (const int*)d_in[0];
  const float* enc = (const float*)d_in[1];
  const float* self_mask = (const float*)d_in[2];
  const float* cross_mask = (const float*)d_in[3];
  const float* emb = (const float*)d_in[4];
  const float* Wq_s = (const float*)d_in[5];
  const float* Wk_s = (const float*)d_in[6];
  const float* Wv_s = (const float*)d_in[7];
  const float* bq_s = (const float*)d_in[8];
  const float* bk_s = (const float*)d_in[9];
  const float* bv_s = (const float*)d_in[10];
  const float* Wq_c = (const float*)d_in[11];
  const float* Wk_c = (const float*)d_in[12];
  const float* Wv_c = (const float*)d_in[13];
  const float* bq_c = (const float*)d_in[14];
  const float* bk_c = (const float*)d_in[15];
  const float* bv_c = (const float*)d_in[16];
  const float* W1 = (const float*)d_in[17];
  const float* b1 = (const float*)d_in[18];
  const float* W2 = (const float*)d_in[19];
  const float* b2 = (const float*)d_in[20];
  const float* ln1_g = (const float*)d_in[21];
  const float* ln1_b = (const float*)d_in[22];
  const float* ln2_g = (const float*)d_in[23];
  const float* ln2_b = (const float*)d_in[24];

  char* ws = (char*)d_ws;
  float* x = (float*)(ws);                        // 8 MB
  float* tmp = (float*)(ws + (8u << 20));         // 8 MB
  float* qb = (float*)(ws + (16u << 20));         // 8 MB
  float* kb = (float*)(ws + (24u << 20));         // 8 MB
  float* vb = (float*)(ws + (32u << 20));         // 8 MB
  float* ff1 = (float*)(ws + (16u << 20));        // 32 MB (reuses q/k/v)

  const int M = BB * SS;                 // 4096
  const int WSTRIDE = HH * DDIM * DKK;   // 262144 per-layer qkv weight stride
  const int FSTRIDE = DDIM * DFFV;       // 1048576

  dim3 gB(256);
  // embed + PE
  embed_pe_kernel<<<dim3((BB * SS * DDIM + 255) / 256), gB, 0, stream>>>(
      dec, emb, x);

  for (int l = 0; l < NLAYER; l++) {
    const float* wq = Wq_s + (size_t)l * WSTRIDE;
    const float* wk = Wk_s + (size_t)l * WSTRIDE;
    const float* wv = Wv_s + (size_t)l * WSTRIDE;
    // ---- self attention ----
    gemm_bias_kernel<0><<<dim3(8, 64), gB, 0, stream>>>(
        x, wq, bq_s + l * 512, qb, M, 512, 512, DDIM * DKK, DKK, 6);
    gemm_bias_kernel<0><<<dim3(8, 64), gB, 0, stream>>>(
        x, wk, bk_s + l * 512, kb, M, 512, 512, DDIM * DKK, DKK, 6);
    gemm_bias_kernel<0><<<dim3(8, 64), gB, 0, stream>>>(
        x, wv, bv_s + l * 512, vb, M, 512, 512, DDIM * DKK, DKK, 6);
    attn_kernel<<<dim3(SS / 16, HH, BB), gB, 0, stream>>>(qb, kb, vb,
                                                          self_mask, tmp);
    add_ln_kernel<<<dim3(M), dim3(128), 0, stream>>>(x, tmp, ln1_g + l * 512,
                                                     ln1_b + l * 512);
    // ---- cross attention ----
    gemm_bias_kernel<0><<<dim3(8, 64), gB, 0, stream>>>(
        x, Wq_c + (size_t)l * WSTRIDE, bq_c + l * 512, qb, M, 512, 512,
        DDIM * DKK, DKK, 6);
    gemm_bias_kernel<0><<<dim3(8, 64), gB, 0, stream>>>(
        enc, Wk_c + (size_t)l * WSTRIDE, bk_c + l * 512, kb, M, 512, 512,
        DDIM * DKK, DKK, 6);
    gemm_bias_kernel<0><<<dim3(8, 64), gB, 0, stream>>>(
        enc, Wv_c + (size_t)l * WSTRIDE, bv_c + l * 512, vb, M, 512, 512,
        DDIM * DKK, DKK, 6);
    attn_kernel<<<dim3(SS / 16, HH, BB), gB, 0, stream>>>(qb, kb, vb,
                                                          cross_mask, tmp);
    add_ln_kernel<<<dim3(M), dim3(128), 0, stream>>>(x, tmp, ln2_g + l * 512,
                                                     ln2_b + l * 512);
    // ---- feed forward ----
    gemm_bias_kernel<1><<<dim3(32, 64), gB, 0, stream>>>(
        x, W1 + (size_t)l * FSTRIDE, b1 + l * DFFV, ff1, M, DFFV, 512, 0,
        DFFV, 11);
    gemm_bias_kernel<0><<<dim3(8, 64), gB, 0, stream>>>(
        ff1, W2 + (size_t)l * FSTRIDE, b2 + l * 512, tmp, M, 512, DFFV, 0,
        512, 9);
    add_ln_kernel<<<dim3(M), dim3(128), 0, stream>>>(x, tmp, ln2_g + l * 512,
                                                     ln2_b + l * 512);
  }

  hipMemcpyAsync(d_out, x, (size_t)(BB * SS * DDIM) * sizeof(float),
                 hipMemcpyDeviceToDevice, stream);
}

// Round 2
// 1230.586 us; speedup vs baseline: 5.0673x; 5.0673x over previous
//
#include <hip/hip_runtime.h>
#include <hip/hip_bf16.h>
#include <math.h>

#define BB 8
#define SS 512
#define DDIM 512
#define HH 8
#define DKK 64
#define DFFV 2048
#define NLAYER 6
#define EPSV 1e-5f

typedef __attribute__((ext_vector_type(8))) short bf16x8;
typedef __attribute__((ext_vector_type(4))) float f32x4;

static __device__ __forceinline__ ushort f2bf(float f) {
  union { float f; unsigned u; } uf; uf.f = f;
  unsigned u = uf.u;
  unsigned r = (u + 0x7fffu + ((u >> 16) & 1u)) >> 16;
  return (ushort)r;
}

// ---------------- embed + positional encoding (fp32 x + bf16 xb) ----------
__global__ __launch_bounds__(256) void embed_pe_kernel(
    const int* __restrict__ idx, const float* __restrict__ emb,
    float* __restrict__ x, ushort* __restrict__ xb) {
  int t = blockIdx.x * blockDim.x + threadIdx.x;
  if (t >= BB * SS * DDIM) return;
  int d = t & (DDIM - 1);
  int bs = t >> 9;
  int s = bs & (SS - 1);
  int tok = idx[bs];
  int i2 = d & ~1;
  float ang = (float)s * powf(10000.0f, -((float)i2) / (float)DDIM);
  float pe = (d & 1) ? cosf(ang) : sinf(ang);
  float v = emb[tok * DDIM + d] + pe;
  x[t] = v;
  xb[t] = f2bf(v);
}

// ---------------- fp32 -> bf16 cast ----------------
__global__ __launch_bounds__(256) void cast_bf16_kernel(
    const float* __restrict__ in, ushort* __restrict__ out, int n4) {
  int t = blockIdx.x * blockDim.x + threadIdx.x;
  if (t >= n4) return;
  float4 v = reinterpret_cast<const float4*>(in)[t];
  ushort4 o;
  o.x = f2bf(v.x); o.y = f2bf(v.y); o.z = f2bf(v.z); o.w = f2bf(v.w);
  reinterpret_cast<ushort4*>(out)[t] = o;
}

// ---------------- transpose-convert weights: [R][C] fp32 -> [C][R] bf16 ----
__global__ __launch_bounds__(256) void wtrans_kernel(
    const float* __restrict__ in, ushort* __restrict__ out, int R, int C) {
  __shared__ float t[32][33];
  size_t zoff = (size_t)blockIdx.z * R * C;
  const float* ip = in + zoff;
  ushort* op = out + zoff;
  int j = threadIdx.x & 31, i0 = threadIdx.x >> 5;
  int r0 = blockIdx.y * 32, c0 = blockIdx.x * 32;
#pragma unroll
  for (int p = 0; p < 4; p++) {
    int r = r0 + i0 + p * 8;
    t[i0 + p * 8][j] = ip[(size_t)r * C + c0 + j];
  }
  __syncthreads();
#pragma unroll
  for (int p = 0; p < 4; p++) {
    int cc = c0 + i0 + p * 8;
    op[(size_t)cc * R + r0 + j] = f2bf(t[j][i0 + p * 8]);
  }
}

// ---------------- bf16 MFMA GEMM ----------------
// A: [M][K] bf16, Bw: [N][K] bf16, bias fp32[N].
// Tile 128x64, BK=64, 256 threads (4 waves as 2x2 of 64x32).
template <int RELU, int OUTBF>
__global__ __launch_bounds__(256) void gemm_mfma(
    const ushort* __restrict__ A, const ushort* __restrict__ Bw,
    const float* __restrict__ bias, float* __restrict__ Cf,
    ushort* __restrict__ Cb, int M, int N, int K) {
  __shared__ __align__(16) char lds[24576];  // A @0: 128 rows x 128B ; B @16384: 64 rows
  int bn = blockIdx.x * 64, bm = blockIdx.y * 128;
  int tid = threadIdx.x;
  int lane = tid & 63, w = tid >> 6;
  int wm = w >> 1, wn = w & 1;
  int c = lane & 15, g16 = lane >> 4;
  f32x4 acc[4][2] = {};
  for (int k0 = 0; k0 < K; k0 += 64) {
    __syncthreads();
#pragma unroll
    for (int i = 0; i < 4; i++) {
      int e = tid + 256 * i;
      int row = e >> 3, dg = e & 7;
      bf16x8 vv = *(const bf16x8*)(A + (size_t)(bm + row) * K + k0 + dg * 8);
      *(bf16x8*)(lds + row * 128 + ((dg ^ (row & 7)) << 4)) = vv;
    }
#pragma unroll
    for (int i = 0; i < 2; i++) {
      int e = tid + 256 * i;
      int row = e >> 3, dg = e & 7;
      bf16x8 vv = *(const bf16x8*)(Bw + (size_t)(bn + row) * K + k0 + dg * 8);
      *(bf16x8*)(lds + 16384 + row * 128 + ((dg ^ (row & 7)) << 4)) = vv;
    }
    __syncthreads();
#pragma unroll
    for (int ks = 0; ks < 2; ks++) {
      int g = ks * 4 + g16;
      bf16x8 a[4], b[2];
#pragma unroll
      for (int i = 0; i < 4; i++) {
        int row = wm * 64 + i * 16 + c;
        a[i] = *(bf16x8*)(lds + row * 128 + ((g ^ (row & 7)) << 4));
      }
#pragma unroll
      for (int j = 0; j < 2; j++) {
        int row = wn * 32 + j * 16 + c;
        b[j] = *(bf16x8*)(lds + 16384 + row * 128 + ((g ^ (row & 7)) << 4));
      }
#pragma unroll
      for (int i = 0; i < 4; i++)
#pragma unroll
        for (int j = 0; j < 2; j++)
          acc[i][j] = __builtin_amdgcn_mfma_f32_16x16x32_bf16(a[i], b[j],
                                                              acc[i][j], 0, 0, 0);
    }
  }
  // epilogue: C layout col=lane&15, row=(lane>>4)*4+reg
  int rb = g16 * 4;
#pragma unroll
  for (int i = 0; i < 4; i++) {
#pragma unroll
    for (int j = 0; j < 2; j++) {
      int col = bn + wn * 32 + j * 16 + c;
      float bv = bias[col];
#pragma unroll
      for (int qq = 0; qq < 4; qq++) {
        int row = bm + wm * 64 + i * 16 + rb + qq;
        float v = acc[i][j][qq] + bv;
        if (RELU) v = fmaxf(v, 0.0f);
        if (OUTBF)
          Cb[(size_t)row * N + col] = f2bf(v);
        else
          Cf[(size_t)row * N + col] = v;
      }
    }
  }
}

// ---------------- MFMA flash attention ----------------
// q,k,v: bf16 [B*S][H*64]; mask fp32 [B][S][S]; out fp32 [B*S][H*64]
// grid (S/64, H, B), 256 threads; wave w owns q rows q0+16w..+15.
template <int CAUSAL>
__global__ __launch_bounds__(256) void attn_mfma(
    const ushort* __restrict__ q, const ushort* __restrict__ k,
    const ushort* __restrict__ v, const float* __restrict__ mask,
    float* __restrict__ out) {
  __shared__ __align__(16) char lds[24576];  // K @0 (8KB), V^T @8192, P @16384
  int q0 = blockIdx.x * 64, h = blockIdx.y, b = blockIdx.z;
  int tid = threadIdx.x, lane = tid & 63, w = tid >> 6;
  int c = lane & 15, g16 = lane >> 4, rb = g16 * 4;

  bf16x8 qa[2];
#pragma unroll
  for (int ks = 0; ks < 2; ks++)
    qa[ks] = *(const bf16x8*)(q + (size_t)(b * SS + q0 + 16 * w + c) * 512 +
                              h * 64 + ks * 32 + g16 * 8);
  f32x4 o[4] = {};
  float mrow[4], lrow[4];
#pragma unroll
  for (int j = 0; j < 4; j++) { mrow[j] = -1e30f; lrow[j] = 0.f; }

  int ntiles = CAUSAL ? (q0 >> 6) + 1 : 8;
  int pbase = 16384 + w * 2048;
  for (int t = 0; t < ntiles; t++) {
    int kv0 = t * 64;
    __syncthreads();
    // stage K [kv][d] and V^T [dv][kv]
#pragma unroll
    for (int i = 0; i < 2; i++) {
      int e = tid + 256 * i;
      int row = e >> 3, dg = e & 7;
      size_t gaddr = (size_t)(b * SS + kv0 + row) * 512 + h * 64 + dg * 8;
      bf16x8 k8 = *(const bf16x8*)(k + gaddr);
      *(bf16x8*)(lds + row * 128 + ((dg ^ (row & 7)) << 4)) = k8;
      bf16x8 v8 = *(const bf16x8*)(v + gaddr);
#pragma unroll
      for (int jj = 0; jj < 8; jj++) {
        int dv = dg * 8 + jj;
        *(ushort*)(lds + 8192 + dv * 128 + (((row >> 3) ^ (dv & 7)) << 4) +
                   (row & 7) * 2) = (ushort)v8[jj];
      }
    }
    __syncthreads();
    // S = Q K^T
    f32x4 s[4] = {};
#pragma unroll
    for (int ks = 0; ks < 2; ks++) {
      int g = ks * 4 + g16;
#pragma unroll
      for (int f = 0; f < 4; f++) {
        int row = f * 16 + c;
        bf16x8 k8 = *(bf16x8*)(lds + row * 128 + ((g ^ (row & 7)) << 4));
        s[f] = __builtin_amdgcn_mfma_f32_16x16x32_bf16(qa[ks], k8, s[f], 0, 0, 0);
      }
    }
    bool needmask = (!CAUSAL) || (kv0 == q0);
    if (needmask) {
      const float* mp = mask + (size_t)b * SS * SS;
#pragma unroll
      for (int f = 0; f < 4; f++)
#pragma unroll
        for (int j = 0; j < 4; j++)
          s[f][j] = s[f][j] * 0.125f +
                    mp[(size_t)(q0 + 16 * w + rb + j) * SS + kv0 + f * 16 + c];
    } else {
#pragma unroll
      for (int f = 0; f < 4; f++)
#pragma unroll
        for (int j = 0; j < 4; j++) s[f][j] *= 0.125f;
    }
    // online softmax per q-row j (rows live in 16-lane groups)
#pragma unroll
    for (int j = 0; j < 4; j++) {
      float tm = fmaxf(fmaxf(s[0][j], s[1][j]), fmaxf(s[2][j], s[3][j]));
      tm = fmaxf(tm, __shfl_xor(tm, 1));
      tm = fmaxf(tm, __shfl_xor(tm, 2));
      tm = fmaxf(tm, __shfl_xor(tm, 4));
      tm = fmaxf(tm, __shfl_xor(tm, 8));
      float mn = fmaxf(mrow[j], tm);
      float sc = __expf(mrow[j] - mn);
      float p0 = __expf(s[0][j] - mn), p1 = __expf(s[1][j] - mn);
      float p2 = __expf(s[2][j] - mn), p3 = __expf(s[3][j] - mn);
      s[0][j] = p0; s[1][j] = p1; s[2][j] = p2; s[3][j] = p3;
      float ps = p0 + p1 + p2 + p3;
      ps += __shfl_xor(ps, 1);
      ps += __shfl_xor(ps, 2);
      ps += __shfl_xor(ps, 4);
      ps += __shfl_xor(ps, 8);
      lrow[j] = lrow[j] * sc + ps;
      mrow[j] = mn;
      o[0][j] *= sc; o[1][j] *= sc; o[2][j] *= sc; o[3][j] *= sc;
    }
    // P (C-layout) -> per-wave LDS bf16 [16 q rows][64 kv]
#pragma unroll
    for (int f = 0; f < 4; f++) {
      int col = f * 16 + c;
      int cg = col >> 3, cb2 = (col & 7) * 2;
#pragma unroll
      for (int j = 0; j < 4; j++) {
        int r = rb + j;
        *(ushort*)(lds + pbase + r * 128 + ((cg ^ (r & 7)) << 4) + cb2) =
            f2bf(s[f][j]);
      }
    }
    __syncthreads();
    // O += P V
#pragma unroll
    for (int ks2 = 0; ks2 < 2; ks2++) {
      int g = ks2 * 4 + g16;
      bf16x8 pa = *(bf16x8*)(lds + pbase + c * 128 + ((g ^ (c & 7)) << 4));
#pragma unroll
      for (int f = 0; f < 4; f++) {
        int row = f * 16 + c;
        bf16x8 v8 = *(bf16x8*)(lds + 8192 + row * 128 + ((g ^ (row & 7)) << 4));
        o[f] = __builtin_amdgcn_mfma_f32_16x16x32_bf16(pa, v8, o[f], 0, 0, 0);
      }
    }
  }
  // finalize
#pragma unroll
  for (int j = 0; j < 4; j++) {
    float inv = 1.0f / lrow[j];
    size_t rowo = (size_t)(b * SS + q0 + 16 * w + rb + j) * 512 + h * 64;
#pragma unroll
    for (int f = 0; f < 4; f++) out[rowo + f * 16 + c] = o[f][j] * inv;
  }
}

// ---------------- residual add + LayerNorm (fp32 x in place, bf16 copy) ----
__global__ __launch_bounds__(128) void add_ln_kernel(
    float* __restrict__ x, const float* __restrict__ y,
    const float* __restrict__ g, const float* __restrict__ bta,
    ushort* __restrict__ xb) {
  int row = blockIdx.x;
  int tid = threadIdx.x;
  __shared__ float red[2];
  int base = row * DDIM + tid * 4;
  float4 xv = *reinterpret_cast<const float4*>(x + base);
  float4 yv = *reinterpret_cast<const float4*>(y + base);
  float v0 = xv.x + yv.x, v1 = xv.y + yv.y, v2 = xv.z + yv.z, v3 = xv.w + yv.w;
  float s = v0 + v1 + v2 + v3;
#pragma unroll
  for (int off = 32; off > 0; off >>= 1) s += __shfl_xor(s, off);
  int lane = tid & 63, wid = tid >> 6;
  if (lane == 0) red[wid] = s;
  __syncthreads();
  float mean = (red[0] + red[1]) * (1.0f / DDIM);
  float d0 = v0 - mean, d1 = v1 - mean, d2 = v2 - mean, d3 = v3 - mean;
  float t2 = d0 * d0 + d1 * d1 + d2 * d2 + d3 * d3;
#pragma unroll
  for (int off = 32; off > 0; off >>= 1) t2 += __shfl_xor(t2, off);
  __syncthreads();
  if (lane == 0) red[wid] = t2;
  __syncthreads();
  float var = (red[0] + red[1]) * (1.0f / DDIM);
  float rs = rsqrtf(var + EPSV);
  int cidx = tid * 4;
  float4 gv = *reinterpret_cast<const float4*>(g + cidx);
  float4 bv = *reinterpret_cast<const float4*>(bta + cidx);
  float4 o;
  o.x = d0 * rs * gv.x + bv.x;
  o.y = d1 * rs * gv.y + bv.y;
  o.z = d2 * rs * gv.z + bv.z;
  o.w = d3 * rs * gv.w + bv.w;
  *reinterpret_cast<float4*>(x + base) = o;
  ushort4 ob;
  ob.x = f2bf(o.x); ob.y = f2bf(o.y); ob.z = f2bf(o.z); ob.w = f2bf(o.w);
  *reinterpret_cast<ushort4*>(xb + base) = ob;
}

// ---------------- orchestration ----------------
extern "C" void kernel_launch(void* const* d_in, const int* in_sizes, int n_in,
                              void* d_out, int out_size, void* d_ws,
                              size_t ws_size, hipStream_t stream) {
  const int* dec = (const int*)d_in[0];
  const float* enc = (const float*)d_in[1];
  const float* self_mask = (const float*)d_in[2];
  const float* cross_mask = (const float*)d_in[3];
  const float* emb = (const float*)d_in[4];
  const float* Wq_s = (const float*)d_in[5];
  const float* Wk_s = (const float*)d_in[6];
  const float* Wv_s = (const float*)d_in[7];
  const float* bq_s = (const float*)d_in[8];
  const float* bk_s = (const float*)d_in[9];
  const float* bv_s = (const float*)d_in[10];
  const float* Wq_c = (const float*)d_in[11];
  const float* Wk_c = (const float*)d_in[12];
  const float* Wv_c = (const float*)d_in[13];
  const float* bq_c = (const float*)d_in[14];
  const float* bk_c = (const float*)d_in[15];
  const float* bv_c = (const float*)d_in[16];
  const float* W1 = (const float*)d_in[17];
  const float* b1 = (const float*)d_in[18];
  const float* W2 = (const float*)d_in[19];
  const float* b2 = (const float*)d_in[20];
  const float* ln1_g = (const float*)d_in[21];
  const float* ln1_b = (const float*)d_in[22];
  const float* ln2_g = (const float*)d_in[23];
  const float* ln2_b = (const float*)d_in[24];

  char* ws = (char*)d_ws;
  const size_t SZ_QKVW = 3145728ull;  // 6 layers * 512*512 * 2B
  ushort* wqst = (ushort*)(ws + 0 * SZ_QKVW);
  ushort* wkst = (ushort*)(ws + 1 * SZ_QKVW);
  ushort* wvst = (ushort*)(ws + 2 * SZ_QKVW);
  ushort* wqct = (ushort*)(ws + 3 * SZ_QKVW);
  ushort* wkct = (ushort*)(ws + 4 * SZ_QKVW);
  ushort* wvct = (ushort*)(ws + 5 * SZ_QKVW);
  ushort* w1t = (ushort*)(ws + 18874368ull);
  ushort* w2t = (ushort*)(ws + 31457280ull);
  ushort* encb = (ushort*)(ws + 44040192ull);
  ushort* xb = (ushort*)(ws + 48234496ull);
  float* x = (float*)(ws + 52428800ull);
  float* tmp = (float*)(ws + 60817408ull);
  ushort* qb = (ushort*)(ws + 69206016ull);
  ushort* kb = (ushort*)(ws + 73400320ull);
  ushort* vb = (ushort*)(ws + 77594624ull);
  ushort* ff1b = (ushort*)(ws + 69206016ull);  // overlaps qkv (disjoint in time)

  const int M = BB * SS;  // 4096
  dim3 g256(256);

  embed_pe_kernel<<<dim3((BB * SS * DDIM + 255) / 256), g256, 0, stream>>>(
      dec, emb, x, xb);
  cast_bf16_kernel<<<dim3(BB * SS * DDIM / 4 / 256), g256, 0, stream>>>(
      enc, encb, BB * SS * DDIM / 4);

  // weights: per-head [512][64] -> [64][512]; W1 [512][2048] -> [2048][512];
  // W2 [2048][512] -> [512][2048]
  wtrans_kernel<<<dim3(2, 16, 48), g256, 0, stream>>>(Wq_s, wqst, 512, 64);
  wtrans_kernel<<<dim3(2, 16, 48), g256, 0, stream>>>(Wk_s, wkst, 512, 64);
  wtrans_kernel<<<dim3(2, 16, 48), g256, 0, stream>>>(Wv_s, wvst, 512, 64);
  wtrans_kernel<<<dim3(2, 16, 48), g256, 0, stream>>>(Wq_c, wqct, 512, 64);
  wtrans_kernel<<<dim3(2, 16, 48), g256, 0, stream>>>(Wk_c, wkct, 512, 64);
  wtrans_kernel<<<dim3(2, 16, 48), g256, 0, stream>>>(Wv_c, wvct, 512, 64);
  wtrans_kernel<<<dim3(64, 16, 6), g256, 0, stream>>>(W1, w1t, 512, 2048);
  wtrans_kernel<<<dim3(16, 64, 6), g256, 0, stream>>>(W2, w2t, 2048, 512);

  for (int l = 0; l < NLAYER; l++) {
    // ---- self attention ----
    gemm_mfma<0, 1><<<dim3(8, 32), g256, 0, stream>>>(
        xb, wqst + (size_t)l * 262144, bq_s + l * 512, nullptr, qb, M, 512, 512);
    gemm_mfma<0, 1><<<dim3(8, 32), g256, 0, stream>>>(
        xb, wkst + (size_t)l * 262144, bk_s + l * 512, nullptr, kb, M, 512, 512);
    gemm_mfma<0, 1><<<dim3(8, 32), g256, 0, stream>>>(
        xb, wvst + (size_t)l * 262144, bv_s + l * 512, nullptr, vb, M, 512, 512);
    attn_mfma<1><<<dim3(8, 8, 8), g256, 0, stream>>>(qb, kb, vb, self_mask, tmp);
    add_ln_kernel<<<dim3(M), dim3(128), 0, stream>>>(x, tmp, ln1_g + l * 512,
                                                     ln1_b + l * 512, xb);
    // ---- cross attention ----
    gemm_mfma<0, 1><<<dim3(8, 32), g256, 0, stream>>>(
        xb, wqct + (size_t)l * 262144, bq_c + l * 512, nullptr, qb, M, 512, 512);
    gemm_mfma<0, 1><<<dim3(8, 32), g256, 0, stream>>>(
        encb, wkct + (size_t)l * 262144, bk_c + l * 512, nullptr, kb, M, 512, 512);
    gemm_mfma<0, 1><<<dim3(8, 32), g256, 0, stream>>>(
        encb, wvct + (size_t)l * 262144, bv_c + l * 512, nullptr, vb, M, 512, 512);
    attn_mfma<0><<<dim3(8, 8, 8), g256, 0, stream>>>(qb, kb, vb, cross_mask, tmp);
    add_ln_kernel<<<dim3(M), dim3(128), 0, stream>>>(x, tmp, ln2_g + l * 512,
                                                     ln2_b + l * 512, xb);
    // ---- feed forward ----
    gemm_mfma<1, 1><<<dim3(32, 32), g256, 0, stream>>>(
        xb, w1t + (size_t)l * 1048576, b1 + l * DFFV, nullptr, ff1b, M, DFFV, 512);
    gemm_mfma<0, 0><<<dim3(8, 32), g256, 0, stream>>>(
        ff1b, w2t + (size_t)l * 1048576, b2 + l * 512, tmp, nullptr, M, 512, DFFV);
    add_ln_kernel<<<dim3(M), dim3(128), 0, stream>>>(x, tmp, ln2_g + l * 512,
                                                     ln2_b + l * 512, xb);
  }

  hipMemcpyAsync(d_out, x, (size_t)(BB * SS * DDIM) * sizeof(float),
                 hipMemcpyDeviceToDevice, stream);
}

// Round 3
// 1072.753 us; speedup vs baseline: 5.8128x; 1.1471x over previous
//
#include <hip/hip_runtime.h>
#include <hip/hip_bf16.h>
#include <math.h>

#define BB 8
#define SS 512
#define DDIM 512
#define HH 8
#define DFFV 2048
#define NLAYER 6
#define EPSV 1e-5f

typedef __attribute__((ext_vector_type(8))) short bf16x8;
typedef __attribute__((ext_vector_type(4))) float f32x4;

static __device__ __forceinline__ ushort f2bf(float f) {
  union { float f; unsigned u; } uf; uf.f = f;
  unsigned u = uf.u;
  unsigned r = (u + 0x7fffu + ((u >> 16) & 1u)) >> 16;
  return (ushort)r;
}

static __device__ __forceinline__ void gload_lds16(const void* g, void* l) {
  __builtin_amdgcn_global_load_lds(
      (const __attribute__((address_space(1))) void*)g,
      (__attribute__((address_space(3))) void*)l, 16, 0, 0);
}

// ---------------- embed + positional encoding (fp32 x + bf16 xb) ----------
__global__ __launch_bounds__(256) void embed_pe_kernel(
    const int* __restrict__ idx, const float* __restrict__ emb,
    float* __restrict__ x, ushort* __restrict__ xb) {
  int t = blockIdx.x * blockDim.x + threadIdx.x;
  if (t >= BB * SS * DDIM) return;
  int d = t & (DDIM - 1);
  int bs = t >> 9;
  int s = bs & (SS - 1);
  int tok = idx[bs];
  int i2 = d & ~1;
  float ang = (float)s * powf(10000.0f, -((float)i2) / (float)DDIM);
  float pe = (d & 1) ? cosf(ang) : sinf(ang);
  float v = emb[tok * DDIM + d] + pe;
  x[t] = v;
  xb[t] = f2bf(v);
}

// ---------------- fp32 -> bf16 cast ----------------
__global__ __launch_bounds__(256) void cast_bf16_kernel(
    const float* __restrict__ in, ushort* __restrict__ out, int n4) {
  int t = blockIdx.x * blockDim.x + threadIdx.x;
  if (t >= n4) return;
  float4 v = reinterpret_cast<const float4*>(in)[t];
  ushort4 o;
  o.x = f2bf(v.x); o.y = f2bf(v.y); o.z = f2bf(v.z); o.w = f2bf(v.w);
  reinterpret_cast<ushort4*>(out)[t] = o;
}

// ---------------- transpose-convert weights: [R][C] fp32 -> [C][R] bf16 ----
// z -> (l = z>>lgH, h = z&(2^lgH-1)); out at l*zl + h*R*C
__global__ __launch_bounds__(256) void wtrans_kernel(
    const float* __restrict__ in, ushort* __restrict__ out, int R, int C,
    int lgH, size_t zl) {
  __shared__ float t[32][33];
  int z = blockIdx.z;
  int l = z >> lgH, hh = z & ((1 << lgH) - 1);
  const float* ip = in + (size_t)z * R * C;
  ushort* op = out + (size_t)l * zl + (size_t)hh * R * C;
  int j = threadIdx.x & 31, i0 = threadIdx.x >> 5;
  int r0 = blockIdx.y * 32, c0 = blockIdx.x * 32;
#pragma unroll
  for (int p = 0; p < 4; p++) {
    int r = r0 + i0 + p * 8;
    t[i0 + p * 8][j] = ip[(size_t)r * C + c0 + j];
  }
  __syncthreads();
#pragma unroll
  for (int p = 0; p < 4; p++) {
    int cc = c0 + i0 + p * 8;
    op[(size_t)cc * R + r0 + j] = f2bf(t[j][i0 + p * 8]);
  }
}

// ---------------- bias packing ----------------
__global__ __launch_bounds__(256) void pack_bias_kernel(
    const float* __restrict__ bq, const float* __restrict__ bk,
    const float* __restrict__ bv, const float* __restrict__ bkc,
    const float* __restrict__ bvc, float* __restrict__ qkvb,
    float* __restrict__ ckvb) {
  int t = blockIdx.x * 256 + threadIdx.x;
  if (t < NLAYER * 1536) {
    int l = t / 1536, n = t % 1536;
    float v = n < 512 ? bq[l * 512 + n]
                      : (n < 1024 ? bk[l * 512 + n - 512] : bv[l * 512 + n - 1024]);
    qkvb[t] = v;
  }
  if (t < NLAYER * 1024) {
    int l = t / 1024, n = t % 1024;
    ckvb[t] = n < 512 ? bkc[l * 512 + n] : bvc[l * 512 + n - 512];
  }
}

// ---------------- bf16 MFMA GEMM (m97 structure) ----------------
// A:[M][K] bf16, Bw:[N][K] bf16, bias fp32[N]. Tile 128x128, BK=64, 4 waves.
// NTV>0: columns >= NTV are written transposed to vt[b][h][dv][s].
template <int RELU, int OUTBF, int NTV>
__global__ __launch_bounds__(256) void gemm_mfma(
    const ushort* __restrict__ A, const ushort* __restrict__ Bw,
    const float* __restrict__ bias, float* __restrict__ Cf,
    ushort* __restrict__ Cb, ushort* __restrict__ vt, int M, int N, int K) {
  __shared__ __align__(16) ushort Alds[128 * 64];
  __shared__ __align__(16) ushort Blds[128 * 64];
  int bn = blockIdx.x * 128, bm = blockIdx.y * 128;
  int tid = threadIdx.x, lane = tid & 63, w = tid >> 6;
  int wm = w >> 1, wn = w & 1;
  int c = lane & 15, g16 = lane >> 4;
  f32x4 acc[4][4] = {};
  for (int k0 = 0; k0 < K; k0 += 64) {
    __syncthreads();
#pragma unroll
    for (int i = 0; i < 4; i++) {
      int chunk = i * 4 + w;
      int e = chunk * 512 + lane * 8;  // element idx in 128x64 tile
      int row = e >> 6, col = e & 63;
      gload_lds16(A + (size_t)(bm + row) * K + k0 + col,
                  (void*)((char*)Alds + chunk * 1024));
      gload_lds16(Bw + (size_t)(bn + row) * K + k0 + col,
                  (void*)((char*)Blds + chunk * 1024));
    }
    __syncthreads();
#pragma unroll
    for (int ks = 0; ks < 2; ks++) {
      int g = ks * 4 + g16;
      bf16x8 a[4], b[4];
#pragma unroll
      for (int i = 0; i < 4; i++)
        a[i] = *(const bf16x8*)(Alds + (wm * 64 + i * 16 + c) * 64 + g * 8);
#pragma unroll
      for (int j = 0; j < 4; j++)
        b[j] = *(const bf16x8*)(Blds + (wn * 64 + j * 16 + c) * 64 + g * 8);
#pragma unroll
      for (int i = 0; i < 4; i++)
#pragma unroll
        for (int j = 0; j < 4; j++)
          acc[i][j] = __builtin_amdgcn_mfma_f32_16x16x32_bf16(a[i], b[j],
                                                              acc[i][j], 0, 0, 0);
    }
  }
  int rb = g16 * 4;
#pragma unroll
  for (int j = 0; j < 4; j++) {
    int col = bn + wn * 64 + j * 16 + c;
    float bv = bias[col];
    if (NTV > 0 && col >= NTV) {
      int hh = (col - NTV) >> 6, dv = col & 63;
#pragma unroll
      for (int i = 0; i < 4; i++) {
        int row = bm + wm * 64 + i * 16 + rb;
        int b_ = row >> 9, s_ = row & 511;
        ushort4 o4;
        o4.x = f2bf(acc[i][j][0] + bv);
        o4.y = f2bf(acc[i][j][1] + bv);
        o4.z = f2bf(acc[i][j][2] + bv);
        o4.w = f2bf(acc[i][j][3] + bv);
        *reinterpret_cast<ushort4*>(
            vt + ((size_t)(b_ * 8 + hh) * 64 + dv) * 512 + s_) = o4;
      }
    } else {
#pragma unroll
      for (int i = 0; i < 4; i++) {
#pragma unroll
        for (int qq = 0; qq < 4; qq++) {
          int row = bm + wm * 64 + i * 16 + rb + qq;
          float v = acc[i][j][qq] + bv;
          if (RELU) v = fmaxf(v, 0.0f);
          if (OUTBF)
            Cb[(size_t)row * N + col] = f2bf(v);
          else
            Cf[(size_t)row * N + col] = v;
        }
      }
    }
  }
}

// ---------------- MFMA flash attention ----------------
// q: bf16 rows stride qstr (col off h*64); k same with kstr;
// vt: bf16 [b][h][64][512]; mask fp32 [B][S][S]; out fp32 [4096][512]
template <int CAUSAL>
__global__ __launch_bounds__(256) void attn_mfma(
    const ushort* __restrict__ q, int qstr, const ushort* __restrict__ k,
    int kstr, const ushort* __restrict__ vt, const float* __restrict__ mask,
    float* __restrict__ out) {
  __shared__ __align__(16) char lds[24576];  // K @0 (8KB), VT @8192 (8KB), P @16384
  int q0 = blockIdx.x * 64, h = blockIdx.y, b = blockIdx.z;
  int tid = threadIdx.x, lane = tid & 63, w = tid >> 6;
  int c = lane & 15, g16 = lane >> 4, rb = g16 * 4;

  bf16x8 qa[2];
#pragma unroll
  for (int ks = 0; ks < 2; ks++)
    qa[ks] = *(const bf16x8*)(q + (size_t)(b * SS + q0 + 16 * w + c) * qstr +
                              h * 64 + ks * 32 + g16 * 8);
  f32x4 o[4] = {};
  float mrow[4], lrow[4];
#pragma unroll
  for (int j = 0; j < 4; j++) { mrow[j] = -1e30f; lrow[j] = 0.f; }

  int ntiles = CAUSAL ? (q0 >> 6) + 1 : 8;
  int pbase = 16384 + w * 2048;
  for (int t = 0; t < ntiles; t++) {
    int kv0 = t * 64;
    __syncthreads();
#pragma unroll
    for (int i = 0; i < 2; i++) {
      int gr = tid + 256 * i;           // 16B granule id, 0..511
      int row = gr >> 3, col8 = gr & 7;
      bf16x8 k8 = *(const bf16x8*)(k + (size_t)(b * SS + kv0 + row) * kstr +
                                   h * 64 + col8 * 8);
      *(bf16x8*)(lds + row * 128 + ((col8 ^ (row & 7)) << 4)) = k8;
      bf16x8 v8 = *(const bf16x8*)(vt + ((size_t)(b * 8 + h) * 64 + row) * 512 +
                                   kv0 + col8 * 8);
      *(bf16x8*)(lds + 8192 + row * 128 + ((col8 ^ (row & 7)) << 4)) = v8;
    }
    __syncthreads();
    // S = Q K^T
    f32x4 s[4] = {};
#pragma unroll
    for (int ks = 0; ks < 2; ks++) {
      int g = ks * 4 + g16;
#pragma unroll
      for (int f = 0; f < 4; f++) {
        int row = f * 16 + c;
        bf16x8 k8 = *(bf16x8*)(lds + row * 128 + ((g ^ (row & 7)) << 4));
        s[f] = __builtin_amdgcn_mfma_f32_16x16x32_bf16(qa[ks], k8, s[f], 0, 0, 0);
      }
    }
    bool needmask = (!CAUSAL) || (kv0 == q0);
    if (needmask) {
      const float* mp = mask + (size_t)b * SS * SS;
#pragma unroll
      for (int f = 0; f < 4; f++)
#pragma unroll
        for (int j = 0; j < 4; j++)
          s[f][j] = s[f][j] * 0.125f +
                    mp[(size_t)(q0 + 16 * w + rb + j) * SS + kv0 + f * 16 + c];
    } else {
#pragma unroll
      for (int f = 0; f < 4; f++)
#pragma unroll
        for (int j = 0; j < 4; j++) s[f][j] *= 0.125f;
    }
    // online softmax (rows in 16-lane groups)
#pragma unroll
    for (int j = 0; j < 4; j++) {
      float tm = fmaxf(fmaxf(s[0][j], s[1][j]), fmaxf(s[2][j], s[3][j]));
      tm = fmaxf(tm, __shfl_xor(tm, 1));
      tm = fmaxf(tm, __shfl_xor(tm, 2));
      tm = fmaxf(tm, __shfl_xor(tm, 4));
      tm = fmaxf(tm, __shfl_xor(tm, 8));
      float mn = fmaxf(mrow[j], tm);
      float sc = __expf(mrow[j] - mn);
      float p0 = __expf(s[0][j] - mn), p1 = __expf(s[1][j] - mn);
      float p2 = __expf(s[2][j] - mn), p3 = __expf(s[3][j] - mn);
      s[0][j] = p0; s[1][j] = p1; s[2][j] = p2; s[3][j] = p3;
      float ps = p0 + p1 + p2 + p3;
      ps += __shfl_xor(ps, 1);
      ps += __shfl_xor(ps, 2);
      ps += __shfl_xor(ps, 4);
      ps += __shfl_xor(ps, 8);
      lrow[j] = lrow[j] * sc + ps;
      mrow[j] = mn;
      o[0][j] *= sc; o[1][j] *= sc; o[2][j] *= sc; o[3][j] *= sc;
    }
    // P (C-layout) -> per-wave LDS bf16 [16 q rows][64 kv]
#pragma unroll
    for (int f = 0; f < 4; f++) {
      int col = f * 16 + c;
      int cg = col >> 3, cb2 = (col & 7) * 2;
#pragma unroll
      for (int j = 0; j < 4; j++) {
        int r = rb + j;
        *(ushort*)(lds + pbase + r * 128 + ((cg ^ (r & 7)) << 4) + cb2) =
            f2bf(s[f][j]);
      }
    }
    // O += P V
#pragma unroll
    for (int ks2 = 0; ks2 < 2; ks2++) {
      int g = ks2 * 4 + g16;
      bf16x8 pa = *(bf16x8*)(lds + pbase + c * 128 + ((g ^ (c & 7)) << 4));
#pragma unroll
      for (int f = 0; f < 4; f++) {
        int row = f * 16 + c;
        bf16x8 v8 = *(bf16x8*)(lds + 8192 + row * 128 + ((g ^ (row & 7)) << 4));
        o[f] = __builtin_amdgcn_mfma_f32_16x16x32_bf16(pa, v8, o[f], 0, 0, 0);
      }
    }
  }
#pragma unroll
  for (int j = 0; j < 4; j++) {
    float inv = 1.0f / lrow[j];
    size_t rowo = (size_t)(b * SS + q0 + 16 * w + rb + j) * 512 + h * 64;
#pragma unroll
    for (int f = 0; f < 4; f++) out[rowo + f * 16 + c] = o[f][j] * inv;
  }
}

// ---------------- residual add + LayerNorm (wave per row) ----------------
__global__ __launch_bounds__(256) void add_ln_kernel(
    float* __restrict__ x, const float* __restrict__ y,
    const float* __restrict__ g, const float* __restrict__ bta,
    ushort* __restrict__ xb) {
  int row = blockIdx.x * 4 + (threadIdx.x >> 6);
  int lane = threadIdx.x & 63;
  int base = row * DDIM + lane * 8;
  float4 x0 = *reinterpret_cast<const float4*>(x + base);
  float4 x1 = *reinterpret_cast<const float4*>(x + base + 4);
  float4 y0 = *reinterpret_cast<const float4*>(y + base);
  float4 y1 = *reinterpret_cast<const float4*>(y + base + 4);
  float v[8] = {x0.x + y0.x, x0.y + y0.y, x0.z + y0.z, x0.w + y0.w,
                x1.x + y1.x, x1.y + y1.y, x1.z + y1.z, x1.w + y1.w};
  float s = 0.f;
#pragma unroll
  for (int i = 0; i < 8; i++) s += v[i];
#pragma unroll
  for (int off = 32; off > 0; off >>= 1) s += __shfl_xor(s, off);
  float mean = s * (1.0f / DDIM);
  float t2 = 0.f;
#pragma unroll
  for (int i = 0; i < 8; i++) {
    v[i] -= mean;
    t2 += v[i] * v[i];
  }
#pragma unroll
  for (int off = 32; off > 0; off >>= 1) t2 += __shfl_xor(t2, off);
  float rs = rsqrtf(t2 * (1.0f / DDIM) + EPSV);
  int cidx = lane * 8;
  float4 g0 = *reinterpret_cast<const float4*>(g + cidx);
  float4 g1 = *reinterpret_cast<const float4*>(g + cidx + 4);
  float4 b0 = *reinterpret_cast<const float4*>(bta + cidx);
  float4 b1 = *reinterpret_cast<const float4*>(bta + cidx + 4);
  float o[8];
  o[0] = v[0] * rs * g0.x + b0.x; o[1] = v[1] * rs * g0.y + b0.y;
  o[2] = v[2] * rs * g0.z + b0.z; o[3] = v[3] * rs * g0.w + b0.w;
  o[4] = v[4] * rs * g1.x + b1.x; o[5] = v[5] * rs * g1.y + b1.y;
  o[6] = v[6] * rs * g1.z + b1.z; o[7] = v[7] * rs * g1.w + b1.w;
  float4 w0 = {o[0], o[1], o[2], o[3]}, w1 = {o[4], o[5], o[6], o[7]};
  *reinterpret_cast<float4*>(x + base) = w0;
  *reinterpret_cast<float4*>(x + base + 4) = w1;
  ushort4 ob0, ob1;
  ob0.x = f2bf(o[0]); ob0.y = f2bf(o[1]); ob0.z = f2bf(o[2]); ob0.w = f2bf(o[3]);
  ob1.x = f2bf(o[4]); ob1.y = f2bf(o[5]); ob1.z = f2bf(o[6]); ob1.w = f2bf(o[7]);
  *reinterpret_cast<ushort4*>(xb + base) = ob0;
  *reinterpret_cast<ushort4*>(xb + base + 4) = ob1;
}

// ---------------- orchestration ----------------
extern "C" void kernel_launch(void* const* d_in, const int* in_sizes, int n_in,
                              void* d_out, int out_size, void* d_ws,
                              size_t ws_size, hipStream_t stream) {
  const int* dec = (const int*)d_in[0];
  const float* enc = (const float*)d_in[1];
  const float* self_mask = (const float*)d_in[2];
  const float* cross_mask = (const float*)d_in[3];
  const float* emb = (const float*)d_in[4];
  const float* Wq_s = (const float*)d_in[5];
  const float* Wk_s = (const float*)d_in[6];
  const float* Wv_s = (const float*)d_in[7];
  const float* bq_s = (const float*)d_in[8];
  const float* bk_s = (const float*)d_in[9];
  const float* bv_s = (const float*)d_in[10];
  const float* Wq_c = (const float*)d_in[11];
  const float* Wk_c = (const float*)d_in[12];
  const float* Wv_c = (const float*)d_in[13];
  const float* bq_c = (const float*)d_in[14];
  const float* bk_c = (const float*)d_in[15];
  const float* bv_c = (const float*)d_in[16];
  const float* W1 = (const float*)d_in[17];
  const float* b1 = (const float*)d_in[18];
  const float* W2 = (const float*)d_in[19];
  const float* b2 = (const float*)d_in[20];
  const float* ln1_g = (const float*)d_in[21];
  const float* ln1_b = (const float*)d_in[22];
  const float* ln2_g = (const float*)d_in[23];
  const float* ln2_b = (const float*)d_in[24];

  char* ws = (char*)d_ws;
  ushort* wqkv = (ushort*)(ws + 0);              // 6*1536*512*2 = 9437184
  ushort* wqc = (ushort*)(ws + 9437184ull);      // 3145728
  ushort* wckv = (ushort*)(ws + 12582912ull);    // 6291456
  ushort* w1t = (ushort*)(ws + 18874368ull);     // 12582912
  ushort* w2t = (ushort*)(ws + 31457280ull);     // 12582912
  ushort* encb = (ushort*)(ws + 44040192ull);    // 4194304
  ushort* xb = (ushort*)(ws + 48234496ull);      // 4194304
  float* x = (float*)(ws + 52428800ull);         // 8388608
  float* tmp = (float*)(ws + 60817408ull);       // 8388608
  // time-shared big region (16.8 MB):
  ushort* qkvbuf = (ushort*)(ws + 69206016ull);  // [4096][1536]
  ushort* cq = (ushort*)(ws + 69206016ull);      // [4096][512]
  ushort* ckv = (ushort*)(ws + 73400320ull);     // [4096][1024]
  ushort* ff1b = (ushort*)(ws + 69206016ull);    // [4096][2048]
  ushort* vt = (ushort*)(ws + 85983232ull);      // 4194304
  float* qkvbias = (float*)(ws + 90177536ull);   // 6*1536*4
  float* ckvbias = (float*)(ws + 90214400ull);   // 6*1024*4

  const int M = BB * SS;  // 4096
  dim3 g256(256);

  embed_pe_kernel<<<dim3((M * DDIM + 255) / 256), g256, 0, stream>>>(dec, emb,
                                                                     x, xb);
  cast_bf16_kernel<<<dim3(M * DDIM / 4 / 256), g256, 0, stream>>>(
      enc, encb, M * DDIM / 4);
  pack_bias_kernel<<<dim3(36), g256, 0, stream>>>(bq_s, bk_s, bv_s, bk_c, bv_c,
                                                  qkvbias, ckvbias);

  wtrans_kernel<<<dim3(2, 16, 48), g256, 0, stream>>>(Wq_s, wqkv, 512, 64, 3,
                                                      786432ull);
  wtrans_kernel<<<dim3(2, 16, 48), g256, 0, stream>>>(Wk_s, wqkv + 262144, 512,
                                                      64, 3, 786432ull);
  wtrans_kernel<<<dim3(2, 16, 48), g256, 0, stream>>>(Wv_s, wqkv + 524288, 512,
                                                      64, 3, 786432ull);
  wtrans_kernel<<<dim3(2, 16, 48), g256, 0, stream>>>(Wq_c, wqc, 512, 64, 3,
                                                      262144ull);
  wtrans_kernel<<<dim3(2, 16, 48), g256, 0, stream>>>(Wk_c, wckv, 512, 64, 3,
                                                      524288ull);
  wtrans_kernel<<<dim3(2, 16, 48), g256, 0, stream>>>(Wv_c, wckv + 262144, 512,
                                                      64, 3, 524288ull);
  wtrans_kernel<<<dim3(64, 16, 6), g256, 0, stream>>>(W1, w1t, 512, 2048, 0,
                                                      1048576ull);
  wtrans_kernel<<<dim3(16, 64, 6), g256, 0, stream>>>(W2, w2t, 2048, 512, 0,
                                                      1048576ull);

  for (int l = 0; l < NLAYER; l++) {
    // ---- self attention: fused QKV GEMM (V transposed to vt) ----
    gemm_mfma<0, 1, 1024><<<dim3(12, 32), g256, 0, stream>>>(
        xb, wqkv + (size_t)l * 786432, qkvbias + l * 1536, nullptr, qkvbuf, vt,
        M, 1536, 512);
    attn_mfma<1><<<dim3(8, 8, 8), g256, 0, stream>>>(
        qkvbuf, 1536, qkvbuf + 512, 1536, vt, self_mask, tmp);
    add_ln_kernel<<<dim3(M / 4), g256, 0, stream>>>(x, tmp, ln1_g + l * 512,
                                                    ln1_b + l * 512, xb);
    // ---- cross attention ----
    gemm_mfma<0, 1, 0><<<dim3(4, 32), g256, 0, stream>>>(
        xb, wqc + (size_t)l * 262144, bq_c + l * 512, nullptr, cq, nullptr, M,
        512, 512);
    gemm_mfma<0, 1, 512><<<dim3(8, 32), g256, 0, stream>>>(
        encb, wckv + (size_t)l * 524288, ckvbias + l * 1024, nullptr, ckv, vt,
        M, 1024, 512);
    attn_mfma<0><<<dim3(8, 8, 8), g256, 0, stream>>>(cq, 512, ckv, 1024, vt,
                                                     cross_mask, tmp);
    add_ln_kernel<<<dim3(M / 4), g256, 0, stream>>>(x, tmp, ln2_g + l * 512,
                                                    ln2_b + l * 512, xb);
    // ---- feed forward ----
    gemm_mfma<1, 1, 0><<<dim3(16, 32), g256, 0, stream>>>(
        xb, w1t + (size_t)l * 1048576, b1 + l * DFFV, nullptr, ff1b, nullptr,
        M, DFFV, 512);
    gemm_mfma<0, 0, 0><<<dim3(4, 32), g256, 0, stream>>>(
        ff1b, w2t + (size_t)l * 1048576, b2 + l * 512, tmp, nullptr, nullptr,
        M, 512, DFFV);
    add_ln_kernel<<<dim3(M / 4), g256, 0, stream>>>(x, tmp, ln2_g + l * 512,
                                                    ln2_b + l * 512, xb);
  }

  hipMemcpyAsync(d_out, x, (size_t)M * DDIM * sizeof(float),
                 hipMemcpyDeviceToDevice, stream);
}

// Round 4
// 860.933 us; speedup vs baseline: 7.2430x; 1.2460x over previous
//
#include <hip/hip_runtime.h>
#include <hip/hip_bf16.h>
#include <math.h>

#define BB 8
#define SS 512
#define DDIM 512
#define HH 8
#define DFFV 2048
#define NLAYER 6
#define EPSV 1e-5f

typedef __attribute__((ext_vector_type(8))) short bf16x8;
typedef __attribute__((ext_vector_type(4))) float f32x4;

static __device__ __forceinline__ ushort f2bf(float f) {
  union { float f; unsigned u; } uf; uf.f = f;
  unsigned u = uf.u;
  unsigned r = (u + 0x7fffu + ((u >> 16) & 1u)) >> 16;
  return (ushort)r;
}

static __device__ __forceinline__ void gload_lds16(const void* g, void* l) {
  __builtin_amdgcn_global_load_lds(
      (const __attribute__((address_space(1))) void*)g,
      (__attribute__((address_space(3))) void*)l, 16, 0, 0);
}

// ---------------- embed + positional encoding (fp32 x + bf16 xb) ----------
__global__ __launch_bounds__(256) void embed_pe_kernel(
    const int* __restrict__ idx, const float* __restrict__ emb,
    float* __restrict__ x, ushort* __restrict__ xb) {
  int t = blockIdx.x * blockDim.x + threadIdx.x;
  if (t >= BB * SS * DDIM) return;
  int d = t & (DDIM - 1);
  int bs = t >> 9;
  int s = bs & (SS - 1);
  int tok = idx[bs];
  int i2 = d & ~1;
  float ang = (float)s * powf(10000.0f, -((float)i2) / (float)DDIM);
  float pe = (d & 1) ? cosf(ang) : sinf(ang);
  float v = emb[tok * DDIM + d] + pe;
  x[t] = v;
  xb[t] = f2bf(v);
}

// ---------------- fp32 -> bf16 cast ----------------
__global__ __launch_bounds__(256) void cast_bf16_kernel(
    const float* __restrict__ in, ushort* __restrict__ out, int n4) {
  int t = blockIdx.x * blockDim.x + threadIdx.x;
  if (t >= n4) return;
  float4 v = reinterpret_cast<const float4*>(in)[t];
  ushort4 o;
  o.x = f2bf(v.x); o.y = f2bf(v.y); o.z = f2bf(v.z); o.w = f2bf(v.w);
  reinterpret_cast<ushort4*>(out)[t] = o;
}

// ---------------- transpose-convert weights: [R][C] fp32 -> [C][R] bf16 ----
__global__ __launch_bounds__(256) void wtrans_kernel(
    const float* __restrict__ in, ushort* __restrict__ out, int R, int C,
    int lgH, size_t zl) {
  __shared__ float t[32][33];
  int z = blockIdx.z;
  int l = z >> lgH, hh = z & ((1 << lgH) - 1);
  const float* ip = in + (size_t)z * R * C;
  ushort* op = out + (size_t)l * zl + (size_t)hh * R * C;
  int j = threadIdx.x & 31, i0 = threadIdx.x >> 5;
  int r0 = blockIdx.y * 32, c0 = blockIdx.x * 32;
#pragma unroll
  for (int p = 0; p < 4; p++) {
    int r = r0 + i0 + p * 8;
    t[i0 + p * 8][j] = ip[(size_t)r * C + c0 + j];
  }
  __syncthreads();
#pragma unroll
  for (int p = 0; p < 4; p++) {
    int cc = c0 + i0 + p * 8;
    op[(size_t)cc * R + r0 + j] = f2bf(t[j][i0 + p * 8]);
  }
}

// ---------------- bias packing ----------------
__global__ __launch_bounds__(256) void pack_bias_kernel(
    const float* __restrict__ bq, const float* __restrict__ bk,
    const float* __restrict__ bv, const float* __restrict__ bkc,
    const float* __restrict__ bvc, float* __restrict__ qkvb,
    float* __restrict__ ckvb) {
  int t = blockIdx.x * 256 + threadIdx.x;
  if (t < NLAYER * 1536) {
    int l = t / 1536, n = t % 1536;
    float v = n < 512 ? bq[l * 512 + n]
                      : (n < 1024 ? bk[l * 512 + n - 512] : bv[l * 512 + n - 1024]);
    qkvb[t] = v;
  }
  if (t < NLAYER * 1024) {
    int l = t / 1024, n = t % 1024;
    ckvb[t] = n < 512 ? bkc[l * 512 + n] : bvc[l * 512 + n - 512];
  }
}

// ---------------- bf16 MFMA GEMM ----------------
// A:[M][K] bf16, Bw:[N][K] bf16, bias fp32[N]. Tile BMxBN, BK=64, 4 waves.
// LDS XOR-swizzled via pre-swizzled global source (linear gload_lds dest).
// NTV>0: columns >= NTV are written transposed to vt[b][h][dv][s].
template <int BM, int BN, int RELU, int OUTBF, int NTV>
__global__ __launch_bounds__(256) void gemm_mfma(
    const ushort* __restrict__ A, const ushort* __restrict__ Bw,
    const float* __restrict__ bias, float* __restrict__ Cf,
    ushort* __restrict__ Cb, ushort* __restrict__ vt, int M, int N, int K) {
  constexpr int WM = BM / 64;   // waves along M
  constexpr int WN = 4 / WM;    // waves along N
  constexpr int W = BN / WN;    // wave tile width
  constexpr int BF = W / 16;    // B fragments per wave
  constexpr int GA = BM * 8;    // A granules (16B) per K-step
  constexpr int GPT = (BM + BN) * 8 / 256;
  __shared__ __align__(16) ushort lds_s[(BM + BN) * 64];
  ushort* Alds = lds_s;
  ushort* Blds = lds_s + BM * 64;
  int bn = blockIdx.x * BN, bm = blockIdx.y * BM;
  int tid = threadIdx.x, lane = tid & 63, w = tid >> 6;
  int wm = w / WN, wn = w % WN;
  int c = lane & 15, g16 = lane >> 4;
  f32x4 acc[4][BF] = {};
  for (int k0 = 0; k0 < K; k0 += 64) {
    __syncthreads();
#pragma unroll
    for (int i = 0; i < GPT; i++) {
      int gidx = i * 256 + tid;
      int gbase = (i * 4 + w) * 64;  // wave-uniform LDS granule base
      if (gidx < GA) {
        int row = gidx >> 3, dg = gidx & 7;
        gload_lds16(A + (size_t)(bm + row) * K + k0 + ((dg ^ (row & 7)) << 3),
                    (void*)((char*)lds_s + gbase * 16));
      } else {
        int bidx = gidx - GA;
        int row = bidx >> 3, dg = bidx & 7;
        gload_lds16(Bw + (size_t)(bn + row) * K + k0 + ((dg ^ (row & 7)) << 3),
                    (void*)((char*)lds_s + gbase * 16));
      }
    }
    __syncthreads();
#pragma unroll
    for (int ks = 0; ks < 2; ks++) {
      int g = ks * 4 + g16;
      bf16x8 a[4], b[BF];
#pragma unroll
      for (int i = 0; i < 4; i++) {
        int R = wm * 64 + i * 16 + c;
        a[i] = *(const bf16x8*)(Alds + R * 64 + ((g ^ (R & 7)) << 3));
      }
#pragma unroll
      for (int j = 0; j < BF; j++) {
        int Rb = wn * W + j * 16 + c;
        b[j] = *(const bf16x8*)(Blds + Rb * 64 + ((g ^ (Rb & 7)) << 3));
      }
#pragma unroll
      for (int i = 0; i < 4; i++)
#pragma unroll
        for (int j = 0; j < BF; j++)
          acc[i][j] = __builtin_amdgcn_mfma_f32_16x16x32_bf16(a[i], b[j],
                                                              acc[i][j], 0, 0, 0);
    }
  }
  int rb = g16 * 4;
#pragma unroll
  for (int j = 0; j < BF; j++) {
    int col = bn + wn * W + j * 16 + c;
    float bv = bias[col];
    if (NTV > 0 && col >= NTV) {
      int hh = (col - NTV) >> 6, dv = col & 63;
#pragma unroll
      for (int i = 0; i < 4; i++) {
        int row = bm + wm * 64 + i * 16 + rb;
        int b_ = row >> 9, s_ = row & 511;
        ushort4 o4;
        o4.x = f2bf(acc[i][j][0] + bv);
        o4.y = f2bf(acc[i][j][1] + bv);
        o4.z = f2bf(acc[i][j][2] + bv);
        o4.w = f2bf(acc[i][j][3] + bv);
        *reinterpret_cast<ushort4*>(
            vt + ((size_t)(b_ * 8 + hh) * 64 + dv) * 512 + s_) = o4;
      }
    } else {
#pragma unroll
      for (int i = 0; i < 4; i++) {
#pragma unroll
        for (int qq = 0; qq < 4; qq++) {
          int row = bm + wm * 64 + i * 16 + rb + qq;
          float v = acc[i][j][qq] + bv;
          if (RELU) v = fmaxf(v, 0.0f);
          if (OUTBF)
            Cb[(size_t)row * N + col] = f2bf(v);
          else
            Cf[(size_t)row * N + col] = v;
        }
      }
    }
  }
}

// ---------------- MFMA flash attention ----------------
// q: bf16 rows stride qstr (col off h*64); k same with kstr;
// vt: bf16 [b][h][64][512]; mask fp32 [B][S][S] (MASKED=1: causal);
// out fp32 [4096][512].  MASKED=0: no mask at all (cross, zeros).
template <int MASKED>
__global__ __launch_bounds__(256) void attn_mfma(
    const ushort* __restrict__ q, int qstr, const ushort* __restrict__ k,
    int kstr, const ushort* __restrict__ vt, const float* __restrict__ mask,
    float* __restrict__ out) {
  __shared__ __align__(16) char lds[24576];  // K @0 (8KB), VT @8192 (8KB), P @16384
  int q0 = blockIdx.x * 64, h = blockIdx.y, b = blockIdx.z;
  int tid = threadIdx.x, lane = tid & 63, w = tid >> 6;
  int c = lane & 15, g16 = lane >> 4, rb = g16 * 4;

  bf16x8 qa[2];
#pragma unroll
  for (int ks = 0; ks < 2; ks++)
    qa[ks] = *(const bf16x8*)(q + (size_t)(b * SS + q0 + 16 * w + c) * qstr +
                              h * 64 + ks * 32 + g16 * 8);
  f32x4 o[4] = {};
  float mrow[4], lrow[4];
#pragma unroll
  for (int j = 0; j < 4; j++) { mrow[j] = -1e30f; lrow[j] = 0.f; }

  int ntiles = MASKED ? (q0 >> 6) + 1 : 8;
  int pbase = 16384 + w * 2048;
  for (int t = 0; t < ntiles; t++) {
    int kv0 = t * 64;
    __syncthreads();
#pragma unroll
    for (int i = 0; i < 2; i++) {
      int gr = tid + 256 * i;           // 16B granule id, 0..511
      int row = gr >> 3, col8 = gr & 7;
      bf16x8 k8 = *(const bf16x8*)(k + (size_t)(b * SS + kv0 + row) * kstr +
                                   h * 64 + col8 * 8);
      *(bf16x8*)(lds + row * 128 + ((col8 ^ (row & 7)) << 4)) = k8;
      bf16x8 v8 = *(const bf16x8*)(vt + ((size_t)(b * 8 + h) * 64 + row) * 512 +
                                   kv0 + col8 * 8);
      *(bf16x8*)(lds + 8192 + row * 128 + ((col8 ^ (row & 7)) << 4)) = v8;
    }
    __syncthreads();
    // S = Q K^T
    f32x4 s[4] = {};
#pragma unroll
    for (int ks = 0; ks < 2; ks++) {
      int g = ks * 4 + g16;
#pragma unroll
      for (int f = 0; f < 4; f++) {
        int row = f * 16 + c;
        bf16x8 k8 = *(bf16x8*)(lds + row * 128 + ((g ^ (row & 7)) << 4));
        s[f] = __builtin_amdgcn_mfma_f32_16x16x32_bf16(qa[ks], k8, s[f], 0, 0, 0);
      }
    }
    if (MASKED && kv0 == q0) {
      const float* mp = mask + (size_t)b * SS * SS;
#pragma unroll
      for (int f = 0; f < 4; f++)
#pragma unroll
        for (int j = 0; j < 4; j++)
          s[f][j] = s[f][j] * 0.125f +
                    mp[(size_t)(q0 + 16 * w + rb + j) * SS + kv0 + f * 16 + c];
    } else {
#pragma unroll
      for (int f = 0; f < 4; f++)
#pragma unroll
        for (int j = 0; j < 4; j++) s[f][j] *= 0.125f;
    }
    // online softmax (rows in 16-lane groups)
#pragma unroll
    for (int j = 0; j < 4; j++) {
      float tm = fmaxf(fmaxf(s[0][j], s[1][j]), fmaxf(s[2][j], s[3][j]));
      tm = fmaxf(tm, __shfl_xor(tm, 1));
      tm = fmaxf(tm, __shfl_xor(tm, 2));
      tm = fmaxf(tm, __shfl_xor(tm, 4));
      tm = fmaxf(tm, __shfl_xor(tm, 8));
      float mn = fmaxf(mrow[j], tm);
      float sc = __expf(mrow[j] - mn);
      float p0 = __expf(s[0][j] - mn), p1 = __expf(s[1][j] - mn);
      float p2 = __expf(s[2][j] - mn), p3 = __expf(s[3][j] - mn);
      s[0][j] = p0; s[1][j] = p1; s[2][j] = p2; s[3][j] = p3;
      float ps = p0 + p1 + p2 + p3;
      ps += __shfl_xor(ps, 1);
      ps += __shfl_xor(ps, 2);
      ps += __shfl_xor(ps, 4);
      ps += __shfl_xor(ps, 8);
      lrow[j] = lrow[j] * sc + ps;
      mrow[j] = mn;
      o[0][j] *= sc; o[1][j] *= sc; o[2][j] *= sc; o[3][j] *= sc;
    }
    // P (C-layout) -> per-wave LDS bf16 [16 q rows][64 kv]
#pragma unroll
    for (int f = 0; f < 4; f++) {
      int col = f * 16 + c;
      int cg = col >> 3, cb2 = (col & 7) * 2;
#pragma unroll
      for (int j = 0; j < 4; j++) {
        int r = rb + j;
        *(ushort*)(lds + pbase + r * 128 + ((cg ^ (r & 7)) << 4) + cb2) =
            f2bf(s[f][j]);
      }
    }
    // O += P V
#pragma unroll
    for (int ks2 = 0; ks2 < 2; ks2++) {
      int g = ks2 * 4 + g16;
      bf16x8 pa = *(bf16x8*)(lds + pbase + c * 128 + ((g ^ (c & 7)) << 4));
#pragma unroll
      for (int f = 0; f < 4; f++) {
        int row = f * 16 + c;
        bf16x8 v8 = *(bf16x8*)(lds + 8192 + row * 128 + ((g ^ (row & 7)) << 4));
        o[f] = __builtin_amdgcn_mfma_f32_16x16x32_bf16(pa, v8, o[f], 0, 0, 0);
      }
    }
  }
#pragma unroll
  for (int j = 0; j < 4; j++) {
    float inv = 1.0f / lrow[j];
    size_t rowo = (size_t)(b * SS + q0 + 16 * w + rb + j) * 512 + h * 64;
#pragma unroll
    for (int f = 0; f < 4; f++) out[rowo + f * 16 + c] = o[f][j] * inv;
  }
}

// ---------------- residual add + LayerNorm (wave per row) ----------------
__global__ __launch_bounds__(256) void add_ln_kernel(
    float* __restrict__ x, const float* __restrict__ y,
    const float* __restrict__ g, const float* __restrict__ bta,
    ushort* __restrict__ xb) {
  int row = blockIdx.x * 4 + (threadIdx.x >> 6);
  int lane = threadIdx.x & 63;
  int base = row * DDIM + lane * 8;
  float4 x0 = *reinterpret_cast<const float4*>(x + base);
  float4 x1 = *reinterpret_cast<const float4*>(x + base + 4);
  float4 y0 = *reinterpret_cast<const float4*>(y + base);
  float4 y1 = *reinterpret_cast<const float4*>(y + base + 4);
  float v[8] = {x0.x + y0.x, x0.y + y0.y, x0.z + y0.z, x0.w + y0.w,
                x1.x + y1.x, x1.y + y1.y, x1.z + y1.z, x1.w + y1.w};
  float s = 0.f;
#pragma unroll
  for (int i = 0; i < 8; i++) s += v[i];
#pragma unroll
  for (int off = 32; off > 0; off >>= 1) s += __shfl_xor(s, off);
  float mean = s * (1.0f / DDIM);
  float t2 = 0.f;
#pragma unroll
  for (int i = 0; i < 8; i++) {
    v[i] -= mean;
    t2 += v[i] * v[i];
  }
#pragma unroll
  for (int off = 32; off > 0; off >>= 1) t2 += __shfl_xor(t2, off);
  float rs = rsqrtf(t2 * (1.0f / DDIM) + EPSV);
  int cidx = lane * 8;
  float4 g0 = *reinterpret_cast<const float4*>(g + cidx);
  float4 g1 = *reinterpret_cast<const float4*>(g + cidx + 4);
  float4 b0 = *reinterpret_cast<const float4*>(bta + cidx);
  float4 b1 = *reinterpret_cast<const float4*>(bta + cidx + 4);
  float o[8];
  o[0] = v[0] * rs * g0.x + b0.x; o[1] = v[1] * rs * g0.y + b0.y;
  o[2] = v[2] * rs * g0.z + b0.z; o[3] = v[3] * rs * g0.w + b0.w;
  o[4] = v[4] * rs * g1.x + b1.x; o[5] = v[5] * rs * g1.y + b1.y;
  o[6] = v[6] * rs * g1.z + b1.z; o[7] = v[7] * rs * g1.w + b1.w;
  float4 w0 = {o[0], o[1], o[2], o[3]}, w1 = {o[4], o[5], o[6], o[7]};
  *reinterpret_cast<float4*>(x + base) = w0;
  *reinterpret_cast<float4*>(x + base + 4) = w1;
  ushort4 ob0, ob1;
  ob0.x = f2bf(o[0]); ob0.y = f2bf(o[1]); ob0.z = f2bf(o[2]); ob0.w = f2bf(o[3]);
  ob1.x = f2bf(o[4]); ob1.y = f2bf(o[5]); ob1.z = f2bf(o[6]); ob1.w = f2bf(o[7]);
  *reinterpret_cast<ushort4*>(xb + base) = ob0;
  *reinterpret_cast<ushort4*>(xb + base + 4) = ob1;
}

// ---------------- orchestration ----------------
extern "C" void kernel_launch(void* const* d_in, const int* in_sizes, int n_in,
                              void* d_out, int out_size, void* d_ws,
                              size_t ws_size, hipStream_t stream) {
  const int* dec = (const int*)d_in[0];
  const float* enc = (const float*)d_in[1];
  const float* self_mask = (const float*)d_in[2];
  const float* cross_mask = (const float*)d_in[3];
  const float* emb = (const float*)d_in[4];
  const float* Wq_s = (const float*)d_in[5];
  const float* Wk_s = (const float*)d_in[6];
  const float* Wv_s = (const float*)d_in[7];
  const float* bq_s = (const float*)d_in[8];
  const float* bk_s = (const float*)d_in[9];
  const float* bv_s = (const float*)d_in[10];
  const float* Wq_c = (const float*)d_in[11];
  const float* Wk_c = (const float*)d_in[12];
  const float* Wv_c = (const float*)d_in[13];
  const float* bq_c = (const float*)d_in[14];
  const float* bk_c = (const float*)d_in[15];
  const float* bv_c = (const float*)d_in[16];
  const float* W1 = (const float*)d_in[17];
  const float* b1 = (const float*)d_in[18];
  const float* W2 = (const float*)d_in[19];
  const float* b2 = (const float*)d_in[20];
  const float* ln1_g = (const float*)d_in[21];
  const float* ln1_b = (const float*)d_in[22];
  const float* ln2_g = (const float*)d_in[23];
  const float* ln2_b = (const float*)d_in[24];

  char* ws = (char*)d_ws;
  ushort* wqkv = (ushort*)(ws + 0);              // 9437184
  ushort* wqc = (ushort*)(ws + 9437184ull);      // 3145728
  ushort* wckv = (ushort*)(ws + 12582912ull);    // 6291456
  ushort* w1t = (ushort*)(ws + 18874368ull);     // 12582912
  ushort* w2t = (ushort*)(ws + 31457280ull);     // 12582912
  ushort* encb = (ushort*)(ws + 44040192ull);    // 4194304
  ushort* xb = (ushort*)(ws + 48234496ull);      // 4194304
  float* x = (float*)(ws + 52428800ull);         // 8388608
  float* tmp = (float*)(ws + 60817408ull);       // 8388608
  ushort* qkvbuf = (ushort*)(ws + 69206016ull);  // [4096][1536]
  ushort* cq = (ushort*)(ws + 69206016ull);      // [4096][512]
  ushort* ckv = (ushort*)(ws + 73400320ull);     // [4096][1024]
  ushort* ff1b = (ushort*)(ws + 69206016ull);    // [4096][2048]
  ushort* vt = (ushort*)(ws + 85983232ull);      // 4194304
  float* qkvbias = (float*)(ws + 90177536ull);
  float* ckvbias = (float*)(ws + 90214400ull);

  const int M = BB * SS;  // 4096
  dim3 g256(256);

  embed_pe_kernel<<<dim3((M * DDIM + 255) / 256), g256, 0, stream>>>(dec, emb,
                                                                     x, xb);
  cast_bf16_kernel<<<dim3(M * DDIM / 4 / 256), g256, 0, stream>>>(
      enc, encb, M * DDIM / 4);
  pack_bias_kernel<<<dim3(36), g256, 0, stream>>>(bq_s, bk_s, bv_s, bk_c, bv_c,
                                                  qkvbias, ckvbias);

  wtrans_kernel<<<dim3(2, 16, 48), g256, 0, stream>>>(Wq_s, wqkv, 512, 64, 3,
                                                      786432ull);
  wtrans_kernel<<<dim3(2, 16, 48), g256, 0, stream>>>(Wk_s, wqkv + 262144, 512,
                                                      64, 3, 786432ull);
  wtrans_kernel<<<dim3(2, 16, 48), g256, 0, stream>>>(Wv_s, wqkv + 524288, 512,
                                                      64, 3, 786432ull);
  wtrans_kernel<<<dim3(2, 16, 48), g256, 0, stream>>>(Wq_c, wqc, 512, 64, 3,
                                                      262144ull);
  wtrans_kernel<<<dim3(2, 16, 48), g256, 0, stream>>>(Wk_c, wckv, 512, 64, 3,
                                                      524288ull);
  wtrans_kernel<<<dim3(2, 16, 48), g256, 0, stream>>>(Wv_c, wckv + 262144, 512,
                                                      64, 3, 524288ull);
  wtrans_kernel<<<dim3(64, 16, 6), g256, 0, stream>>>(W1, w1t, 512, 2048, 0,
                                                      1048576ull);
  wtrans_kernel<<<dim3(16, 64, 6), g256, 0, stream>>>(W2, w2t, 2048, 512, 0,
                                                      1048576ull);

  for (int l = 0; l < NLAYER; l++) {
    // ---- self attention: fused QKV GEMM (V transposed to vt) ----
    gemm_mfma<64, 128, 0, 1, 1024><<<dim3(12, 64), g256, 0, stream>>>(
        xb, wqkv + (size_t)l * 786432, qkvbias + l * 1536, nullptr, qkvbuf, vt,
        M, 1536, 512);
    attn_mfma<1><<<dim3(8, 8, 8), g256, 0, stream>>>(
        qkvbuf, 1536, qkvbuf + 512, 1536, vt, self_mask, tmp);
    add_ln_kernel<<<dim3(M / 4), g256, 0, stream>>>(x, tmp, ln1_g + l * 512,
                                                    ln1_b + l * 512, xb);
    // ---- cross attention ----
    gemm_mfma<64, 64, 0, 1, 0><<<dim3(8, 64), g256, 0, stream>>>(
        xb, wqc + (size_t)l * 262144, bq_c + l * 512, nullptr, cq, nullptr, M,
        512, 512);
    gemm_mfma<64, 128, 0, 1, 512><<<dim3(8, 64), g256, 0, stream>>>(
        encb, wckv + (size_t)l * 524288, ckvbias + l * 1024, nullptr, ckv, vt,
        M, 1024, 512);
    attn_mfma<0><<<dim3(8, 8, 8), g256, 0, stream>>>(cq, 512, ckv, 1024, vt,
                                                     cross_mask, tmp);
    add_ln_kernel<<<dim3(M / 4), g256, 0, stream>>>(x, tmp, ln2_g + l * 512,
                                                    ln2_b + l * 512, xb);
    // ---- feed forward ----
    gemm_mfma<64, 128, 1, 1, 0><<<dim3(16, 64), g256, 0, stream>>>(
        xb, w1t + (size_t)l * 1048576, b1 + l * DFFV, nullptr, ff1b, nullptr,
        M, DFFV, 512);
    gemm_mfma<64, 64, 0, 0, 0><<<dim3(8, 64), g256, 0, stream>>>(
        ff1b, w2t + (size_t)l * 1048576, b2 + l * 512, tmp, nullptr, nullptr,
        M, 512, DFFV);
    add_ln_kernel<<<dim3(M / 4), g256, 0, stream>>>(x, tmp, ln2_g + l * 512,
                                                    ln2_b + l * 512, xb);
  }

  hipMemcpyAsync(d_out, x, (size_t)M * DDIM * sizeof(float),
                 hipMemcpyDeviceToDevice, stream);
}

// Round 5
// 813.337 us; speedup vs baseline: 7.6668x; 1.0585x over previous
//
#include <hip/hip_runtime.h>
#include <hip/hip_bf16.h>
#include <math.h>

#define BB 8
#define SS 512
#define DDIM 512
#define HH 8
#define DFFV 2048
#define NLAYER 6
#define EPSV 1e-5f

typedef __attribute__((ext_vector_type(8))) short bf16x8;
typedef __attribute__((ext_vector_type(4))) float f32x4;

static __device__ __forceinline__ ushort f2bf(float f) {
  union { float f; unsigned u; } uf; uf.f = f;
  unsigned u = uf.u;
  unsigned r = (u + 0x7fffu + ((u >> 16) & 1u)) >> 16;
  return (ushort)r;
}

static __device__ __forceinline__ void gload_lds16(const void* g, void* l) {
  __builtin_amdgcn_global_load_lds(
      (const __attribute__((address_space(1))) void*)g,
      (__attribute__((address_space(3))) void*)l, 16, 0, 0);
}

// ---------------- embed + positional encoding (fp32 x + bf16 xb) ----------
__global__ __launch_bounds__(256) void embed_pe_kernel(
    const int* __restrict__ idx, const float* __restrict__ emb,
    float* __restrict__ x, ushort* __restrict__ xb) {
  int t = blockIdx.x * blockDim.x + threadIdx.x;
  if (t >= BB * SS * DDIM) return;
  int d = t & (DDIM - 1);
  int bs = t >> 9;
  int s = bs & (SS - 1);
  int tok = idx[bs];
  int i2 = d & ~1;
  float ang = (float)s * powf(10000.0f, -((float)i2) / (float)DDIM);
  float pe = (d & 1) ? cosf(ang) : sinf(ang);
  float v = emb[tok * DDIM + d] + pe;
  x[t] = v;
  xb[t] = f2bf(v);
}

// ---------------- fp32 -> bf16 cast ----------------
__global__ __launch_bounds__(256) void cast_bf16_kernel(
    const float* __restrict__ in, ushort* __restrict__ out, int n4) {
  int t = blockIdx.x * blockDim.x + threadIdx.x;
  if (t >= n4) return;
  float4 v = reinterpret_cast<const float4*>(in)[t];
  ushort4 o;
  o.x = f2bf(v.x); o.y = f2bf(v.y); o.z = f2bf(v.z); o.w = f2bf(v.w);
  reinterpret_cast<ushort4*>(out)[t] = o;
}

// ---------------- transpose-convert weights: [R][C] fp32 -> [C][R] bf16 ----
__global__ __launch_bounds__(256) void wtrans_kernel(
    const float* __restrict__ in, ushort* __restrict__ out, int R, int C,
    int lgH, size_t zl) {
  __shared__ float t[32][33];
  int z = blockIdx.z;
  int l = z >> lgH, hh = z & ((1 << lgH) - 1);
  const float* ip = in + (size_t)z * R * C;
  ushort* op = out + (size_t)l * zl + (size_t)hh * R * C;
  int j = threadIdx.x & 31, i0 = threadIdx.x >> 5;
  int r0 = blockIdx.y * 32, c0 = blockIdx.x * 32;
#pragma unroll
  for (int p = 0; p < 4; p++) {
    int r = r0 + i0 + p * 8;
    t[i0 + p * 8][j] = ip[(size_t)r * C + c0 + j];
  }
  __syncthreads();
#pragma unroll
  for (int p = 0; p < 4; p++) {
    int cc = c0 + i0 + p * 8;
    op[(size_t)cc * R + r0 + j] = f2bf(t[j][i0 + p * 8]);
  }
}

// ---------------- bias packing ----------------
__global__ __launch_bounds__(256) void pack_bias_kernel(
    const float* __restrict__ bq, const float* __restrict__ bk,
    const float* __restrict__ bv, const float* __restrict__ bkc,
    const float* __restrict__ bvc, float* __restrict__ qkvb,
    float* __restrict__ ckvb) {
  int t = blockIdx.x * 256 + threadIdx.x;
  if (t < NLAYER * 1536) {
    int l = t / 1536, n = t % 1536;
    float v = n < 512 ? bq[l * 512 + n]
                      : (n < 1024 ? bk[l * 512 + n - 512] : bv[l * 512 + n - 1024]);
    qkvb[t] = v;
  }
  if (t < NLAYER * 1024) {
    int l = t / 1024, n = t % 1024;
    ckvb[t] = n < 512 ? bkc[l * 512 + n] : bvc[l * 512 + n - 512];
  }
}

// ---------------- bf16 MFMA GEMM, 2-phase pipelined (counted vmcnt) -------
// A:[M][K] bf16, Bw:[N][K] bf16, bias fp32[N]. Tile BMxBN, BK=64, 4 waves.
// LDS double-buffered; XOR-swizzle via pre-swizzled global source.
// NTV>0: cols with (cc = LGP? col&((1<<LGP)-1) : col) >= NTV are written
// transposed to vt[lp][b][h][dv][s], lp = LGP? col>>LGP : 0.
template <int BM, int BN, int RELU, int OUTBF, int NTV, int LGP>
__global__ __launch_bounds__(256) void gemm_mfma(
    const ushort* __restrict__ A, const ushort* __restrict__ Bw,
    const float* __restrict__ bias, float* __restrict__ Cf,
    ushort* __restrict__ Cb, ushort* __restrict__ vt, int M, int N, int K) {
  constexpr int WM = BM / 64;   // waves along M
  constexpr int WN = 4 / WM;    // waves along N
  constexpr int W = BN / WN;    // wave tile width
  constexpr int BF = W / 16;    // B fragments per wave
  constexpr int GA = BM * 8;    // A granules (16B) per K-step
  constexpr int GPT = (BM + BN) * 8 / 256;  // gload instrs per thread per stage
  __shared__ __align__(16) ushort lds_s[2][(BM + BN) * 64];
  int bn = blockIdx.x * BN, bm = blockIdx.y * BM;
  int tid = threadIdx.x, lane = tid & 63, w = tid >> 6;
  int wm = w / WN, wn = w % WN;
  int c = lane & 15, g16 = lane >> 4;
  f32x4 acc[4][BF] = {};

  auto STAGE = [&](int k0, int bufi) {
#pragma unroll
    for (int i = 0; i < GPT; i++) {
      int gidx = i * 256 + tid;
      int gbase = (i * 4 + w) * 64;  // wave-uniform LDS granule base
      const ushort* src;
      if (gidx < GA) {
        int row = gidx >> 3, dg = gidx & 7;
        src = A + (size_t)(bm + row) * K + k0 + ((dg ^ (row & 7)) << 3);
      } else {
        int bidx = gidx - GA;
        int row = bidx >> 3, dg = bidx & 7;
        src = Bw + (size_t)(bn + row) * K + k0 + ((dg ^ (row & 7)) << 3);
      }
      gload_lds16(src, (void*)((char*)(&lds_s[bufi][0]) + gbase * 16));
    }
  };

  int nk = K >> 6;
  STAGE(0, 0);
  for (int kt = 0; kt < nk; kt++) {
    int cur = kt & 1;
    if (kt + 1 < nk) {
      STAGE((kt + 1) << 6, cur ^ 1);
      asm volatile("s_waitcnt vmcnt(%0)" ::"n"(GPT) : "memory");
    } else {
      asm volatile("s_waitcnt vmcnt(0)" ::: "memory");
    }
    __builtin_amdgcn_s_barrier();
    __builtin_amdgcn_sched_barrier(0);
    const ushort* Alds = &lds_s[cur][0];
    const ushort* Blds = &lds_s[cur][BM * 64];
#pragma unroll
    for (int ks = 0; ks < 2; ks++) {
      int g = ks * 4 + g16;
      bf16x8 a[4], b[BF];
#pragma unroll
      for (int i = 0; i < 4; i++) {
        int R = wm * 64 + i * 16 + c;
        a[i] = *(const bf16x8*)(Alds + R * 64 + ((g ^ (R & 7)) << 3));
      }
#pragma unroll
      for (int j = 0; j < BF; j++) {
        int Rb = wn * W + j * 16 + c;
        b[j] = *(const bf16x8*)(Blds + Rb * 64 + ((g ^ (Rb & 7)) << 3));
      }
#pragma unroll
      for (int i = 0; i < 4; i++)
#pragma unroll
        for (int j = 0; j < BF; j++)
          acc[i][j] = __builtin_amdgcn_mfma_f32_16x16x32_bf16(a[i], b[j],
                                                              acc[i][j], 0, 0, 0);
    }
    __builtin_amdgcn_sched_barrier(0);
    __builtin_amdgcn_s_barrier();
  }
  int rb = g16 * 4;
#pragma unroll
  for (int j = 0; j < BF; j++) {
    int col = bn + wn * W + j * 16 + c;
    float bv = bias[col];
    int cc = LGP ? (col & ((1 << LGP) - 1)) : col;
    int lp = LGP ? (col >> LGP) : 0;
    if (NTV > 0 && cc >= NTV) {
      int hh = (cc - NTV) >> 6, dv = col & 63;
      ushort* vtl = vt + (size_t)lp * 2097152;
#pragma unroll
      for (int i = 0; i < 4; i++) {
        int row = bm + wm * 64 + i * 16 + rb;
        int b_ = row >> 9, s_ = row & 511;
        ushort4 o4;
        o4.x = f2bf(acc[i][j][0] + bv);
        o4.y = f2bf(acc[i][j][1] + bv);
        o4.z = f2bf(acc[i][j][2] + bv);
        o4.w = f2bf(acc[i][j][3] + bv);
        *reinterpret_cast<ushort4*>(
            vtl + ((size_t)(b_ * 8 + hh) * 64 + dv) * 512 + s_) = o4;
      }
    } else {
#pragma unroll
      for (int i = 0; i < 4; i++) {
#pragma unroll
        for (int qq = 0; qq < 4; qq++) {
          int row = bm + wm * 64 + i * 16 + rb + qq;
          float v = acc[i][j][qq] + bv;
          if (RELU) v = fmaxf(v, 0.0f);
          if (OUTBF)
            Cb[(size_t)row * N + col] = f2bf(v);
          else
            Cf[(size_t)row * N + col] = v;
        }
      }
    }
  }
}

// ---------------- MFMA flash attention (reg-staged K/V pipeline) ----------
// q: bf16 rows stride qstr (col off h*64); k same with kstr;
// vt: bf16 [b][h][64][512]; out fp32 [4096][512].
// MASKED=1: causal (mask synthesized inline). MASKED=0: no mask.
template <int MASKED>
__global__ __launch_bounds__(256) void attn_mfma(
    const ushort* __restrict__ q, int qstr, const ushort* __restrict__ k,
    int kstr, const ushort* __restrict__ vt, float* __restrict__ out) {
  __shared__ __align__(16) char lds[24576];  // K @0 (8KB), VT @8192 (8KB), P @16384
  int q0 = blockIdx.x * 64, h = blockIdx.y, b = blockIdx.z;
  int tid = threadIdx.x, lane = tid & 63, w = tid >> 6;
  int c = lane & 15, g16 = lane >> 4, rb = g16 * 4;

  bf16x8 qa[2];
#pragma unroll
  for (int ks = 0; ks < 2; ks++)
    qa[ks] = *(const bf16x8*)(q + (size_t)(b * SS + q0 + 16 * w + c) * qstr +
                              h * 64 + ks * 32 + g16 * 8);
  f32x4 o[4] = {};
  float mrow[4], lrow[4];
#pragma unroll
  for (int j = 0; j < 4; j++) { mrow[j] = -1e30f; lrow[j] = 0.f; }

  int nt = MASKED ? (q0 >> 6) + 1 : 8;
  int pbase = 16384 + w * 2048;

  int row0 = tid >> 3, c8 = tid & 7;
  int row1 = row0 + 32;  // (tid+256)>>3
  const ushort* vbase = vt + ((size_t)(b * 8 + h) * 64) * 512;
  bf16x8 rk0, rk1, rv0, rv1;
  auto LOADT = [&](int kv0) {
    rk0 = *(const bf16x8*)(k + (size_t)(b * SS + kv0 + row0) * kstr + h * 64 +
                           c8 * 8);
    rk1 = *(const bf16x8*)(k + (size_t)(b * SS + kv0 + row1) * kstr + h * 64 +
                           c8 * 8);
    rv0 = *(const bf16x8*)(vbase + (size_t)row0 * 512 + kv0 + c8 * 8);
    rv1 = *(const bf16x8*)(vbase + (size_t)row1 * 512 + kv0 + c8 * 8);
  };
  auto WRT = [&]() {
    *(bf16x8*)(lds + row0 * 128 + ((c8 ^ (row0 & 7)) << 4)) = rk0;
    *(bf16x8*)(lds + row1 * 128 + ((c8 ^ (row1 & 7)) << 4)) = rk1;
    *(bf16x8*)(lds + 8192 + row0 * 128 + ((c8 ^ (row0 & 7)) << 4)) = rv0;
    *(bf16x8*)(lds + 8192 + row1 * 128 + ((c8 ^ (row1 & 7)) << 4)) = rv1;
  };
  LOADT(0);
  WRT();
  for (int t = 0; t < nt; t++) {
    if (t + 1 < nt) LOADT((t + 1) * 64);
    __syncthreads();
    // S = Q K^T
    f32x4 s[4] = {};
    __builtin_amdgcn_s_setprio(1);
#pragma unroll
    for (int ks = 0; ks < 2; ks++) {
      int g = ks * 4 + g16;
#pragma unroll
      for (int f = 0; f < 4; f++) {
        int row = f * 16 + c;
        bf16x8 k8 = *(bf16x8*)(lds + row * 128 + ((g ^ (row & 7)) << 4));
        s[f] = __builtin_amdgcn_mfma_f32_16x16x32_bf16(qa[ks], k8, s[f], 0, 0, 0);
      }
    }
    __builtin_amdgcn_s_setprio(0);
    if (MASKED && t == nt - 1) {
      // diagonal tile: inline causal mask (kv_local <= q_local keeps)
#pragma unroll
      for (int f = 0; f < 4; f++)
#pragma unroll
        for (int j = 0; j < 4; j++)
          s[f][j] = s[f][j] * 0.125f +
                    ((f * 16 + c) <= (16 * w + rb + j) ? 0.0f : -1e9f);
    } else {
#pragma unroll
      for (int f = 0; f < 4; f++)
#pragma unroll
        for (int j = 0; j < 4; j++) s[f][j] *= 0.125f;
    }
    // online softmax (rows in 16-lane groups)
#pragma unroll
    for (int j = 0; j < 4; j++) {
      float tm = fmaxf(fmaxf(s[0][j], s[1][j]), fmaxf(s[2][j], s[3][j]));
      tm = fmaxf(tm, __shfl_xor(tm, 1));
      tm = fmaxf(tm, __shfl_xor(tm, 2));
      tm = fmaxf(tm, __shfl_xor(tm, 4));
      tm = fmaxf(tm, __shfl_xor(tm, 8));
      float mn = fmaxf(mrow[j], tm);
      float sc = __expf(mrow[j] - mn);
      float p0 = __expf(s[0][j] - mn), p1 = __expf(s[1][j] - mn);
      float p2 = __expf(s[2][j] - mn), p3 = __expf(s[3][j] - mn);
      s[0][j] = p0; s[1][j] = p1; s[2][j] = p2; s[3][j] = p3;
      float ps = p0 + p1 + p2 + p3;
      ps += __shfl_xor(ps, 1);
      ps += __shfl_xor(ps, 2);
      ps += __shfl_xor(ps, 4);
      ps += __shfl_xor(ps, 8);
      lrow[j] = lrow[j] * sc + ps;
      mrow[j] = mn;
      o[0][j] *= sc; o[1][j] *= sc; o[2][j] *= sc; o[3][j] *= sc;
    }
    // P (C-layout) -> per-wave LDS bf16 [16 q rows][64 kv]
#pragma unroll
    for (int f = 0; f < 4; f++) {
      int col = f * 16 + c;
      int cg = col >> 3, cb2 = (col & 7) * 2;
#pragma unroll
      for (int j = 0; j < 4; j++) {
        int r = rb + j;
        *(ushort*)(lds + pbase + r * 128 + ((cg ^ (r & 7)) << 4) + cb2) =
            f2bf(s[f][j]);
      }
    }
    // O += P V
    __builtin_amdgcn_s_setprio(1);
#pragma unroll
    for (int ks2 = 0; ks2 < 2; ks2++) {
      int g = ks2 * 4 + g16;
      bf16x8 pa = *(bf16x8*)(lds + pbase + c * 128 + ((g ^ (c & 7)) << 4));
#pragma unroll
      for (int f = 0; f < 4; f++) {
        int row = f * 16 + c;
        bf16x8 v8 = *(bf16x8*)(lds + 8192 + row * 128 + ((g ^ (row & 7)) << 4));
        o[f] = __builtin_amdgcn_mfma_f32_16x16x32_bf16(pa, v8, o[f], 0, 0, 0);
      }
    }
    __builtin_amdgcn_s_setprio(0);
    __syncthreads();
    if (t + 1 < nt) WRT();
  }
#pragma unroll
  for (int j = 0; j < 4; j++) {
    float inv = 1.0f / lrow[j];
    size_t rowo = (size_t)(b * SS + q0 + 16 * w + rb + j) * 512 + h * 64;
#pragma unroll
    for (int f = 0; f < 4; f++) out[rowo + f * 16 + c] = o[f][j] * inv;
  }
}

// ---------------- residual add + LayerNorm (wave per row) ----------------
__global__ __launch_bounds__(256) void add_ln_kernel(
    float* __restrict__ x, const float* __restrict__ y,
    const float* __restrict__ g, const float* __restrict__ bta,
    ushort* __restrict__ xb) {
  int row = blockIdx.x * 4 + (threadIdx.x >> 6);
  int lane = threadIdx.x & 63;
  int base = row * DDIM + lane * 8;
  float4 x0 = *reinterpret_cast<const float4*>(x + base);
  float4 x1 = *reinterpret_cast<const float4*>(x + base + 4);
  float4 y0 = *reinterpret_cast<const float4*>(y + base);
  float4 y1 = *reinterpret_cast<const float4*>(y + base + 4);
  float v[8] = {x0.x + y0.x, x0.y + y0.y, x0.z + y0.z, x0.w + y0.w,
                x1.x + y1.x, x1.y + y1.y, x1.z + y1.z, x1.w + y1.w};
  float s = 0.f;
#pragma unroll
  for (int i = 0; i < 8; i++) s += v[i];
#pragma unroll
  for (int off = 32; off > 0; off >>= 1) s += __shfl_xor(s, off);
  float mean = s * (1.0f / DDIM);
  float t2 = 0.f;
#pragma unroll
  for (int i = 0; i < 8; i++) {
    v[i] -= mean;
    t2 += v[i] * v[i];
  }
#pragma unroll
  for (int off = 32; off > 0; off >>= 1) t2 += __shfl_xor(t2, off);
  float rs = rsqrtf(t2 * (1.0f / DDIM) + EPSV);
  int cidx = lane * 8;
  float4 g0 = *reinterpret_cast<const float4*>(g + cidx);
  float4 g1 = *reinterpret_cast<const float4*>(g + cidx + 4);
  float4 b0 = *reinterpret_cast<const float4*>(bta + cidx);
  float4 b1 = *reinterpret_cast<const float4*>(bta + cidx + 4);
  float o[8];
  o[0] = v[0] * rs * g0.x + b0.x; o[1] = v[1] * rs * g0.y + b0.y;
  o[2] = v[2] * rs * g0.z + b0.z; o[3] = v[3] * rs * g0.w + b0.w;
  o[4] = v[4] * rs * g1.x + b1.x; o[5] = v[5] * rs * g1.y + b1.y;
  o[6] = v[6] * rs * g1.z + b1.z; o[7] = v[7] * rs * g1.w + b1.w;
  float4 w0 = {o[0], o[1], o[2], o[3]}, w1 = {o[4], o[5], o[6], o[7]};
  *reinterpret_cast<float4*>(x + base) = w0;
  *reinterpret_cast<float4*>(x + base + 4) = w1;
  ushort4 ob0, ob1;
  ob0.x = f2bf(o[0]); ob0.y = f2bf(o[1]); ob0.z = f2bf(o[2]); ob0.w = f2bf(o[3]);
  ob1.x = f2bf(o[4]); ob1.y = f2bf(o[5]); ob1.z = f2bf(o[6]); ob1.w = f2bf(o[7]);
  *reinterpret_cast<ushort4*>(xb + base) = ob0;
  *reinterpret_cast<ushort4*>(xb + base + 4) = ob1;
}

// ---------------- orchestration ----------------
extern "C" void kernel_launch(void* const* d_in, const int* in_sizes, int n_in,
                              void* d_out, int out_size, void* d_ws,
                              size_t ws_size, hipStream_t stream) {
  const int* dec = (const int*)d_in[0];
  const float* enc = (const float*)d_in[1];
  const float* Wq_s = (const float*)d_in[5];
  const float* Wk_s = (const float*)d_in[6];
  const float* Wv_s = (const float*)d_in[7];
  const float* bq_s = (const float*)d_in[8];
  const float* bk_s = (const float*)d_in[9];
  const float* bv_s = (const float*)d_in[10];
  const float* Wq_c = (const float*)d_in[11];
  const float* Wk_c = (const float*)d_in[12];
  const float* Wv_c = (const float*)d_in[13];
  const float* bq_c = (const float*)d_in[14];
  const float* bk_c = (const float*)d_in[15];
  const float* bv_c = (const float*)d_in[16];
  const float* emb = (const float*)d_in[4];
  const float* W1 = (const float*)d_in[17];
  const float* b1 = (const float*)d_in[18];
  const float* W2 = (const float*)d_in[19];
  const float* b2 = (const float*)d_in[20];
  const float* ln1_g = (const float*)d_in[21];
  const float* ln1_b = (const float*)d_in[22];
  const float* ln2_g = (const float*)d_in[23];
  const float* ln2_b = (const float*)d_in[24];

  char* ws = (char*)d_ws;
  ushort* wqkv = (ushort*)(ws + 0);               // 9,437,184
  ushort* wqc = (ushort*)(ws + 9437184ull);       // 3,145,728
  ushort* wckv = (ushort*)(ws + 12582912ull);     // 6,291,456 ([6][1024][512])
  ushort* w1t = (ushort*)(ws + 18874368ull);      // 12,582,912
  ushort* w2t = (ushort*)(ws + 31457280ull);      // 12,582,912
  ushort* encb = (ushort*)(ws + 44040192ull);     // 4,194,304
  ushort* xb = (ushort*)(ws + 48234496ull);       // 4,194,304
  float* x = (float*)(ws + 52428800ull);          // 8,388,608
  float* tmp = (float*)(ws + 60817408ull);        // 8,388,608
  ushort* qkvbuf = (ushort*)(ws + 69206016ull);   // [4096][1536]
  ushort* cq = (ushort*)(ws + 69206016ull);       // [4096][512] (time-shared)
  ushort* ff1b = (ushort*)(ws + 69206016ull);     // [4096][2048] (time-shared)
  ushort* vt = (ushort*)(ws + 85983232ull);       // self V^T, 4,194,304
  float* qkvbias = (float*)(ws + 90177536ull);    // 36,864
  float* ckvbias = (float*)(ws + 90214400ull);    // 24,576
  ushort* ckvbuf = (ushort*)(ws + 90238976ull);   // [4096][6144] = 50,331,648
  ushort* vtc = (ushort*)(ws + 140570624ull);     // [6][8][8][64][512] = 25,165,824

  const int M = BB * SS;  // 4096
  dim3 g256(256);

  embed_pe_kernel<<<dim3((M * DDIM + 255) / 256), g256, 0, stream>>>(dec, emb,
                                                                     x, xb);
  cast_bf16_kernel<<<dim3(M * DDIM / 4 / 256), g256, 0, stream>>>(
      enc, encb, M * DDIM / 4);
  pack_bias_kernel<<<dim3(36), g256, 0, stream>>>(bq_s, bk_s, bv_s, bk_c, bv_c,
                                                  qkvbias, ckvbias);

  wtrans_kernel<<<dim3(2, 16, 48), g256, 0, stream>>>(Wq_s, wqkv, 512, 64, 3,
                                                      786432ull);
  wtrans_kernel<<<dim3(2, 16, 48), g256, 0, stream>>>(Wk_s, wqkv + 262144, 512,
                                                      64, 3, 786432ull);
  wtrans_kernel<<<dim3(2, 16, 48), g256, 0, stream>>>(Wv_s, wqkv + 524288, 512,
                                                      64, 3, 786432ull);
  wtrans_kernel<<<dim3(2, 16, 48), g256, 0, stream>>>(Wq_c, wqc, 512, 64, 3,
                                                      262144ull);
  wtrans_kernel<<<dim3(2, 16, 48), g256, 0, stream>>>(Wk_c, wckv, 512, 64, 3,
                                                      524288ull);
  wtrans_kernel<<<dim3(2, 16, 48), g256, 0, stream>>>(Wv_c, wckv + 262144, 512,
                                                      64, 3, 524288ull);
  wtrans_kernel<<<dim3(64, 16, 6), g256, 0, stream>>>(W1, w1t, 512, 2048, 0,
                                                      1048576ull);
  wtrans_kernel<<<dim3(16, 64, 6), g256, 0, stream>>>(W2, w2t, 2048, 512, 0,
                                                      1048576ull);

  // ---- hoisted cross K/V for ALL layers (depends only on enc) ----
  gemm_mfma<64, 128, 0, 1, 512, 10><<<dim3(48, 64), g256, 0, stream>>>(
      encb, wckv, ckvbias, nullptr, ckvbuf, vtc, M, 6144, 512);

  for (int l = 0; l < NLAYER; l++) {
    // ---- self attention: fused QKV GEMM (V transposed to vt) ----
    gemm_mfma<64, 128, 0, 1, 1024, 0><<<dim3(12, 64), g256, 0, stream>>>(
        xb, wqkv + (size_t)l * 786432, qkvbias + l * 1536, nullptr, qkvbuf, vt,
        M, 1536, 512);
    attn_mfma<1><<<dim3(8, 8, 8), g256, 0, stream>>>(
        qkvbuf, 1536, qkvbuf + 512, 1536, vt, tmp);
    add_ln_kernel<<<dim3(M / 4), g256, 0, stream>>>(x, tmp, ln1_g + l * 512,
                                                    ln1_b + l * 512, xb);
    // ---- cross attention (K/V precomputed) ----
    gemm_mfma<64, 64, 0, 1, 0, 0><<<dim3(8, 64), g256, 0, stream>>>(
        xb, wqc + (size_t)l * 262144, bq_c + l * 512, nullptr, cq, nullptr, M,
        512, 512);
    attn_mfma<0><<<dim3(8, 8, 8), g256, 0, stream>>>(
        cq, 512, ckvbuf + l * 1024, 6144, vtc + (size_t)l * 2097152, tmp);
    add_ln_kernel<<<dim3(M / 4), g256, 0, stream>>>(x, tmp, ln2_g + l * 512,
                                                    ln2_b + l * 512, xb);
    // ---- feed forward ----
    gemm_mfma<64, 128, 1, 1, 0, 0><<<dim3(16, 64), g256, 0, stream>>>(
        xb, w1t + (size_t)l * 1048576, b1 + l * DFFV, nullptr, ff1b, nullptr,
        M, DFFV, 512);
    gemm_mfma<64, 64, 0, 0, 0, 0><<<dim3(8, 64), g256, 0, stream>>>(
        ff1b, w2t + (size_t)l * 1048576, b2 + l * 512, tmp, nullptr, nullptr,
        M, 512, DFFV);
    add_ln_kernel<<<dim3(M / 4), g256, 0, stream>>>(x, tmp, ln2_g + l * 512,
                                                    ln2_b + l * 512, xb);
  }

  hipMemcpyAsync(d_out, x, (size_t)M * DDIM * sizeof(float),
                 hipMemcpyDeviceToDevice, stream);
}

// Round 6
// 747.736 us; speedup vs baseline: 8.3394x; 1.0877x over previous
//
#include <hip/hip_runtime.h>
#include <hip/hip_bf16.h>
#include <math.h>

#define BB 8
#define SS 512
#define DDIM 512
#define HH 8
#define DFFV 2048
#define NLAYER 6
#define EPSV 1e-5f

typedef __attribute__((ext_vector_type(8))) short bf16x8;
typedef __attribute__((ext_vector_type(4))) float f32x4;

static __device__ __forceinline__ ushort f2bf(float f) {
  union { float f; unsigned u; } uf; uf.f = f;
  unsigned u = uf.u;
  unsigned r = (u + 0x7fffu + ((u >> 16) & 1u)) >> 16;
  return (ushort)r;
}
static __device__ __forceinline__ float bf2f(ushort h) {
  union { unsigned u; float f; } x;
  x.u = ((unsigned)h) << 16;
  return x.f;
}

static __device__ __forceinline__ void gload_lds16(const void* g, void* l) {
  __builtin_amdgcn_global_load_lds(
      (const __attribute__((address_space(1))) void*)g,
      (__attribute__((address_space(3))) void*)l, 16, 0, 0);
}

// ---------------- embed + positional encoding (bf16 xb) ----------
__global__ __launch_bounds__(256) void embed_pe_kernel(
    const int* __restrict__ idx, const float* __restrict__ emb,
    ushort* __restrict__ xb) {
  int t = blockIdx.x * blockDim.x + threadIdx.x;
  if (t >= BB * SS * DDIM) return;
  int d = t & (DDIM - 1);
  int bs = t >> 9;
  int s = bs & (SS - 1);
  int tok = idx[bs];
  int i2 = d & ~1;
  float ang = (float)s * powf(10000.0f, -((float)i2) / (float)DDIM);
  float pe = (d & 1) ? cosf(ang) : sinf(ang);
  float v = emb[tok * DDIM + d] + pe;
  xb[t] = f2bf(v);
}

// ---------------- fp32 -> bf16 cast ----------------
__global__ __launch_bounds__(256) void cast_bf16_kernel(
    const float* __restrict__ in, ushort* __restrict__ out, int n4) {
  int t = blockIdx.x * blockDim.x + threadIdx.x;
  if (t >= n4) return;
  float4 v = reinterpret_cast<const float4*>(in)[t];
  ushort4 o;
  o.x = f2bf(v.x); o.y = f2bf(v.y); o.z = f2bf(v.z); o.w = f2bf(v.w);
  reinterpret_cast<ushort4*>(out)[t] = o;
}

// ---------------- transpose-convert weights: [R][C] fp32 -> [C][R] bf16 ----
__global__ __launch_bounds__(256) void wtrans_kernel(
    const float* __restrict__ in, ushort* __restrict__ out, int R, int C,
    int lgH, size_t zl) {
  __shared__ float t[32][33];
  int z = blockIdx.z;
  int l = z >> lgH, hh = z & ((1 << lgH) - 1);
  const float* ip = in + (size_t)z * R * C;
  ushort* op = out + (size_t)l * zl + (size_t)hh * R * C;
  int j = threadIdx.x & 31, i0 = threadIdx.x >> 5;
  int r0 = blockIdx.y * 32, c0 = blockIdx.x * 32;
#pragma unroll
  for (int p = 0; p < 4; p++) {
    int r = r0 + i0 + p * 8;
    t[i0 + p * 8][j] = ip[(size_t)r * C + c0 + j];
  }
  __syncthreads();
#pragma unroll
  for (int p = 0; p < 4; p++) {
    int cc = c0 + i0 + p * 8;
    op[(size_t)cc * R + r0 + j] = f2bf(t[j][i0 + p * 8]);
  }
}

// ---------------- bias packing ----------------
__global__ __launch_bounds__(256) void pack_bias_kernel(
    const float* __restrict__ bq, const float* __restrict__ bk,
    const float* __restrict__ bv, const float* __restrict__ bkc,
    const float* __restrict__ bvc, float* __restrict__ qkvb,
    float* __restrict__ ckvb) {
  int t = blockIdx.x * 256 + threadIdx.x;
  if (t < NLAYER * 1536) {
    int l = t / 1536, n = t % 1536;
    float v = n < 512 ? bq[l * 512 + n]
                      : (n < 1024 ? bk[l * 512 + n - 512] : bv[l * 512 + n - 1024]);
    qkvb[t] = v;
  }
  if (t < NLAYER * 1024) {
    int l = t / 1024, n = t % 1024;
    ckvb[t] = n < 512 ? bkc[l * 512 + n] : bvc[l * 512 + n - 512];
  }
}

// ---------------- bf16 MFMA GEMM, 2-phase pipelined (counted vmcnt) -------
// A:[M][K] bf16, Bw:[N][K] bf16, bias fp32[N]. Tile BMxBN, BK=64, 4 waves.
// LDS double-buffered; XOR-swizzle via pre-swizzled global source.
// SPLITK>1: blockIdx.z picks K-chunk, fp32 partial to Cf + z*M*N (bias z==0).
// NTV>0: cols with (cc = LGP? col&((1<<LGP)-1) : col) >= NTV are written
// transposed to vt[lp][b][h][dv][s], lp = LGP? col>>LGP : 0.
template <int BM, int BN, int RELU, int OUTBF, int NTV, int LGP, int SPLITK>
__global__ __launch_bounds__(256) void gemm_mfma(
    const ushort* __restrict__ A, const ushort* __restrict__ Bw,
    const float* __restrict__ bias, float* __restrict__ Cf,
    ushort* __restrict__ Cb, ushort* __restrict__ vt, int M, int N, int K) {
  constexpr int WM = BM / 64;   // waves along M
  constexpr int WN = 4 / WM;    // waves along N
  constexpr int W = BN / WN;    // wave tile width
  constexpr int AF = 4;         // A fragments per wave (64 rows)
  constexpr int BF = W / 16;    // B fragments per wave
  constexpr int GA = BM * 8;    // A granules (16B) per K-step
  constexpr int GPT = (BM + BN) * 8 / 256;  // gload instrs/thread/stage
  __shared__ __align__(16) ushort lds_s[2][(BM + BN) * 64];
  int bn = blockIdx.x * BN, bm = blockIdx.y * BM;
  int kz = (SPLITK > 1) ? blockIdx.z : 0;
  int Keff = K / SPLITK;
  int kbase = kz * Keff;
  int tid = threadIdx.x, lane = tid & 63, w = tid >> 6;
  int wm = w / WN, wn = w % WN;
  int c = lane & 15, g16 = lane >> 4;
  f32x4 acc[AF][BF] = {};

  auto STAGE = [&](int k0, int bufi) {
#pragma unroll
    for (int i = 0; i < GPT; i++) {
      int gidx = i * 256 + tid;
      int gbase = (i * 4 + w) * 64;  // wave-uniform LDS granule base
      const ushort* src;
      if (gidx < GA) {
        int row = gidx >> 3, dg = gidx & 7;
        src = A + (size_t)(bm + row) * K + kbase + k0 + ((dg ^ (row & 7)) << 3);
      } else {
        int bidx = gidx - GA;
        int row = bidx >> 3, dg = bidx & 7;
        src = Bw + (size_t)(bn + row) * K + kbase + k0 + ((dg ^ (row & 7)) << 3);
      }
      gload_lds16(src, (void*)((char*)(&lds_s[bufi][0]) + gbase * 16));
    }
  };

  int nk = Keff >> 6;
  STAGE(0, 0);
  for (int kt = 0; kt < nk; kt++) {
    int cur = kt & 1;
    if (kt + 1 < nk) {
      STAGE((kt + 1) << 6, cur ^ 1);
      asm volatile("s_waitcnt vmcnt(%0)" ::"n"(GPT) : "memory");
    } else {
      asm volatile("s_waitcnt vmcnt(0)" ::: "memory");
    }
    __builtin_amdgcn_s_barrier();
    __builtin_amdgcn_sched_barrier(0);
    const ushort* Alds = &lds_s[cur][0];
    const ushort* Blds = &lds_s[cur][BM * 64];
#pragma unroll
    for (int ks = 0; ks < 2; ks++) {
      int g = ks * 4 + g16;
      bf16x8 a[AF], b[BF];
#pragma unroll
      for (int i = 0; i < AF; i++) {
        int R = wm * 64 + i * 16 + c;
        a[i] = *(const bf16x8*)(Alds + R * 64 + ((g ^ (R & 7)) << 3));
      }
#pragma unroll
      for (int j = 0; j < BF; j++) {
        int Rb = wn * W + j * 16 + c;
        b[j] = *(const bf16x8*)(Blds + Rb * 64 + ((g ^ (Rb & 7)) << 3));
      }
#pragma unroll
      for (int i = 0; i < AF; i++)
#pragma unroll
        for (int j = 0; j < BF; j++)
          acc[i][j] = __builtin_amdgcn_mfma_f32_16x16x32_bf16(a[i], b[j],
                                                              acc[i][j], 0, 0, 0);
    }
    __builtin_amdgcn_sched_barrier(0);
    __builtin_amdgcn_s_barrier();
  }
  int rb = g16 * 4;
#pragma unroll
  for (int j = 0; j < BF; j++) {
    int col = bn + wn * W + j * 16 + c;
    float bv = (SPLITK > 1 && kz != 0) ? 0.0f : bias[col];
    int cc = LGP ? (col & ((1 << LGP) - 1)) : col;
    int lp = LGP ? (col >> LGP) : 0;
    if (NTV > 0 && cc >= NTV) {
      int hh = (cc - NTV) >> 6, dv = col & 63;
      ushort* vtl = vt + (size_t)lp * 2097152;
#pragma unroll
      for (int i = 0; i < AF; i++) {
        int row = bm + wm * 64 + i * 16 + rb;
        int b_ = row >> 9, s_ = row & 511;
        ushort4 o4;
        o4.x = f2bf(acc[i][j][0] + bv);
        o4.y = f2bf(acc[i][j][1] + bv);
        o4.z = f2bf(acc[i][j][2] + bv);
        o4.w = f2bf(acc[i][j][3] + bv);
        *reinterpret_cast<ushort4*>(
            vtl + ((size_t)(b_ * 8 + hh) * 64 + dv) * 512 + s_) = o4;
      }
    } else {
#pragma unroll
      for (int i = 0; i < AF; i++) {
#pragma unroll
        for (int qq = 0; qq < 4; qq++) {
          int row = bm + wm * 64 + i * 16 + rb + qq;
          float v = acc[i][j][qq] + bv;
          if (RELU) v = fmaxf(v, 0.0f);
          if (OUTBF)
            Cb[(size_t)row * N + col] = f2bf(v);
          else
            Cf[(size_t)kz * M * N + (size_t)row * N + col] = v;
        }
      }
    }
  }
}

// ---------------- MFMA flash attention (dbuf K/V, 1 barrier/tile) ---------
// q: bf16 rows stride qstr (col off h*64); k same with kstr;
// vt: bf16 [b][h][64][512]; out bf16 [4096][512].
// MASKED=1: causal (mask synthesized inline). MASKED=0: no mask.
template <int MASKED>
__global__ __launch_bounds__(256) void attn_mfma(
    const ushort* __restrict__ q, int qstr, const ushort* __restrict__ k,
    int kstr, const ushort* __restrict__ vt, ushort* __restrict__ out) {
  // K0 @0 (8KB), V0 @8192, K1 @16384, V1 @24576, P @32768 (8KB) = 40KB
  __shared__ __align__(16) char lds[40960];
  int q0 = blockIdx.x * 64, h = blockIdx.y, b = blockIdx.z;
  int tid = threadIdx.x, lane = tid & 63, w = tid >> 6;
  int c = lane & 15, g16 = lane >> 4, rb = g16 * 4;

  bf16x8 qa[2];
#pragma unroll
  for (int ks = 0; ks < 2; ks++)
    qa[ks] = *(const bf16x8*)(q + (size_t)(b * SS + q0 + 16 * w + c) * qstr +
                              h * 64 + ks * 32 + g16 * 8);
  f32x4 o[4] = {};
  float mrow[4], lrow[4];
#pragma unroll
  for (int j = 0; j < 4; j++) { mrow[j] = -1e30f; lrow[j] = 0.f; }

  int nt = MASKED ? (q0 >> 6) + 1 : 8;
  int pbase = 32768 + w * 2048;

  int row0 = tid >> 3, c8 = tid & 7;
  int row1 = row0 + 32;
  const ushort* vbase = vt + ((size_t)(b * 8 + h) * 64) * 512;
  bf16x8 rk0, rk1, rv0, rv1;
  auto LOADT = [&](int kv0) {
    rk0 = *(const bf16x8*)(k + (size_t)(b * SS + kv0 + row0) * kstr + h * 64 +
                           c8 * 8);
    rk1 = *(const bf16x8*)(k + (size_t)(b * SS + kv0 + row1) * kstr + h * 64 +
                           c8 * 8);
    rv0 = *(const bf16x8*)(vbase + (size_t)row0 * 512 + kv0 + c8 * 8);
    rv1 = *(const bf16x8*)(vbase + (size_t)row1 * 512 + kv0 + c8 * 8);
  };
  auto WRT = [&](int bufi) {
    char* p = lds + bufi * 16384;
    *(bf16x8*)(p + row0 * 128 + ((c8 ^ (row0 & 7)) << 4)) = rk0;
    *(bf16x8*)(p + row1 * 128 + ((c8 ^ (row1 & 7)) << 4)) = rk1;
    *(bf16x8*)(p + 8192 + row0 * 128 + ((c8 ^ (row0 & 7)) << 4)) = rv0;
    *(bf16x8*)(p + 8192 + row1 * 128 + ((c8 ^ (row1 & 7)) << 4)) = rv1;
  };
  LOADT(0);
  WRT(0);
  for (int t = 0; t < nt; t++) {
    if (t + 1 < nt) LOADT((t + 1) * 64);
    __syncthreads();
    char* kb_ = lds + (t & 1) * 16384;
    char* vb_ = kb_ + 8192;
    // S = Q K^T
    f32x4 s[4] = {};
    __builtin_amdgcn_s_setprio(1);
#pragma unroll
    for (int ks = 0; ks < 2; ks++) {
      int g = ks * 4 + g16;
#pragma unroll
      for (int f = 0; f < 4; f++) {
        int row = f * 16 + c;
        bf16x8 k8 = *(bf16x8*)(kb_ + row * 128 + ((g ^ (row & 7)) << 4));
        s[f] = __builtin_amdgcn_mfma_f32_16x16x32_bf16(qa[ks], k8, s[f], 0, 0, 0);
      }
    }
    __builtin_amdgcn_s_setprio(0);
    if (MASKED && t == nt - 1) {
#pragma unroll
      for (int f = 0; f < 4; f++)
#pragma unroll
        for (int j = 0; j < 4; j++)
          s[f][j] = s[f][j] * 0.125f +
                    ((f * 16 + c) <= (16 * w + rb + j) ? 0.0f : -1e9f);
    } else {
#pragma unroll
      for (int f = 0; f < 4; f++)
#pragma unroll
        for (int j = 0; j < 4; j++) s[f][j] *= 0.125f;
    }
    // online softmax (rows in 16-lane groups)
#pragma unroll
    for (int j = 0; j < 4; j++) {
      float tm = fmaxf(fmaxf(s[0][j], s[1][j]), fmaxf(s[2][j], s[3][j]));
      tm = fmaxf(tm, __shfl_xor(tm, 1));
      tm = fmaxf(tm, __shfl_xor(tm, 2));
      tm = fmaxf(tm, __shfl_xor(tm, 4));
      tm = fmaxf(tm, __shfl_xor(tm, 8));
      float mn = fmaxf(mrow[j], tm);
      float sc = __expf(mrow[j] - mn);
      float p0 = __expf(s[0][j] - mn), p1 = __expf(s[1][j] - mn);
      float p2 = __expf(s[2][j] - mn), p3 = __expf(s[3][j] - mn);
      s[0][j] = p0; s[1][j] = p1; s[2][j] = p2; s[3][j] = p3;
      float ps = p0 + p1 + p2 + p3;
      ps += __shfl_xor(ps, 1);
      ps += __shfl_xor(ps, 2);
      ps += __shfl_xor(ps, 4);
      ps += __shfl_xor(ps, 8);
      lrow[j] = lrow[j] * sc + ps;
      mrow[j] = mn;
      o[0][j] *= sc; o[1][j] *= sc; o[2][j] *= sc; o[3][j] *= sc;
    }
    // P (C-layout) -> per-wave LDS bf16 [16 q rows][64 kv]
#pragma unroll
    for (int f = 0; f < 4; f++) {
      int col = f * 16 + c;
      int cg = col >> 3, cb2 = (col & 7) * 2;
#pragma unroll
      for (int j = 0; j < 4; j++) {
        int r = rb + j;
        *(ushort*)(lds + pbase + r * 128 + ((cg ^ (r & 7)) << 4) + cb2) =
            f2bf(s[f][j]);
      }
    }
    // O += P V
    __builtin_amdgcn_s_setprio(1);
#pragma unroll
    for (int ks2 = 0; ks2 < 2; ks2++) {
      int g = ks2 * 4 + g16;
      bf16x8 pa = *(bf16x8*)(lds + pbase + c * 128 + ((g ^ (c & 7)) << 4));
#pragma unroll
      for (int f = 0; f < 4; f++) {
        int row = f * 16 + c;
        bf16x8 v8 = *(bf16x8*)(vb_ + row * 128 + ((g ^ (row & 7)) << 4));
        o[f] = __builtin_amdgcn_mfma_f32_16x16x32_bf16(pa, v8, o[f], 0, 0, 0);
      }
    }
    __builtin_amdgcn_s_setprio(0);
    if (t + 1 < nt) WRT((t + 1) & 1);
  }
#pragma unroll
  for (int j = 0; j < 4; j++) {
    float inv = 1.0f / lrow[j];
    size_t rowo = (size_t)(b * SS + q0 + 16 * w + rb + j) * 512 + h * 64;
#pragma unroll
    for (int f = 0; f < 4; f++)
      out[rowo + f * 16 + c] = f2bf(o[f][j] * inv);
  }
}

// ---------------- residual add + LayerNorm (bf16 residual, wave/row) ------
// Y2=0: y = bf16 yb.  Y2=1: y = fp32 y0 + fp32 y1 (split-K partials).
// Writes xb (bf16); if xf != nullptr also writes fp32.
template <int Y2>
__global__ __launch_bounds__(256) void add_ln_kernel(
    ushort* __restrict__ xb, const ushort* __restrict__ yb,
    const float* __restrict__ y0, const float* __restrict__ y1,
    const float* __restrict__ g, const float* __restrict__ bta,
    float* __restrict__ xf) {
  int row = blockIdx.x * 4 + (threadIdx.x >> 6);
  int lane = threadIdx.x & 63;
  int base = row * DDIM + lane * 8;
  bf16x8 xv = *reinterpret_cast<const bf16x8*>(xb + base);
  float v[8];
  if (Y2) {
    float4 a0 = *reinterpret_cast<const float4*>(y0 + base);
    float4 a1 = *reinterpret_cast<const float4*>(y0 + base + 4);
    float4 c0 = *reinterpret_cast<const float4*>(y1 + base);
    float4 c1 = *reinterpret_cast<const float4*>(y1 + base + 4);
    v[0] = bf2f((ushort)xv[0]) + a0.x + c0.x;
    v[1] = bf2f((ushort)xv[1]) + a0.y + c0.y;
    v[2] = bf2f((ushort)xv[2]) + a0.z + c0.z;
    v[3] = bf2f((ushort)xv[3]) + a0.w + c0.w;
    v[4] = bf2f((ushort)xv[4]) + a1.x + c1.x;
    v[5] = bf2f((ushort)xv[5]) + a1.y + c1.y;
    v[6] = bf2f((ushort)xv[6]) + a1.z + c1.z;
    v[7] = bf2f((ushort)xv[7]) + a1.w + c1.w;
  } else {
    bf16x8 yv = *reinterpret_cast<const bf16x8*>(yb + base);
#pragma unroll
    for (int i = 0; i < 8; i++)
      v[i] = bf2f((ushort)xv[i]) + bf2f((ushort)yv[i]);
  }
  float s = 0.f;
#pragma unroll
  for (int i = 0; i < 8; i++) s += v[i];
#pragma unroll
  for (int off = 32; off > 0; off >>= 1) s += __shfl_xor(s, off);
  float mean = s * (1.0f / DDIM);
  float t2 = 0.f;
#pragma unroll
  for (int i = 0; i < 8; i++) {
    v[i] -= mean;
    t2 += v[i] * v[i];
  }
#pragma unroll
  for (int off = 32; off > 0; off >>= 1) t2 += __shfl_xor(t2, off);
  float rs = rsqrtf(t2 * (1.0f / DDIM) + EPSV);
  int cidx = lane * 8;
  float4 g0 = *reinterpret_cast<const float4*>(g + cidx);
  float4 g1 = *reinterpret_cast<const float4*>(g + cidx + 4);
  float4 b0 = *reinterpret_cast<const float4*>(bta + cidx);
  float4 b1 = *reinterpret_cast<const float4*>(bta + cidx + 4);
  float o[8];
  o[0] = v[0] * rs * g0.x + b0.x; o[1] = v[1] * rs * g0.y + b0.y;
  o[2] = v[2] * rs * g0.z + b0.z; o[3] = v[3] * rs * g0.w + b0.w;
  o[4] = v[4] * rs * g1.x + b1.x; o[5] = v[5] * rs * g1.y + b1.y;
  o[6] = v[6] * rs * g1.z + b1.z; o[7] = v[7] * rs * g1.w + b1.w;
  bf16x8 ob;
#pragma unroll
  for (int i = 0; i < 8; i++) ob[i] = (short)f2bf(o[i]);
  *reinterpret_cast<bf16x8*>(xb + base) = ob;
  if (xf) {
    float4 w0 = {o[0], o[1], o[2], o[3]}, w1 = {o[4], o[5], o[6], o[7]};
    *reinterpret_cast<float4*>(xf + base) = w0;
    *reinterpret_cast<float4*>(xf + base + 4) = w1;
  }
}

// ---------------- orchestration ----------------
extern "C" void kernel_launch(void* const* d_in, const int* in_sizes, int n_in,
                              void* d_out, int out_size, void* d_ws,
                              size_t ws_size, hipStream_t stream) {
  const int* dec = (const int*)d_in[0];
  const float* enc = (const float*)d_in[1];
  const float* emb = (const float*)d_in[4];
  const float* Wq_s = (const float*)d_in[5];
  const float* Wk_s = (const float*)d_in[6];
  const float* Wv_s = (const float*)d_in[7];
  const float* bq_s = (const float*)d_in[8];
  const float* bk_s = (const float*)d_in[9];
  const float* bv_s = (const float*)d_in[10];
  const float* Wq_c = (const float*)d_in[11];
  const float* Wk_c = (const float*)d_in[12];
  const float* Wv_c = (const float*)d_in[13];
  const float* bq_c = (const float*)d_in[14];
  const float* bk_c = (const float*)d_in[15];
  const float* bv_c = (const float*)d_in[16];
  const float* W1 = (const float*)d_in[17];
  const float* b1 = (const float*)d_in[18];
  const float* W2 = (const float*)d_in[19];
  const float* b2 = (const float*)d_in[20];
  const float* ln1_g = (const float*)d_in[21];
  const float* ln1_b = (const float*)d_in[22];
  const float* ln2_g = (const float*)d_in[23];
  const float* ln2_b = (const float*)d_in[24];

  char* ws = (char*)d_ws;
  ushort* wqkv = (ushort*)(ws + 0);               // 9,437,184
  ushort* wqc = (ushort*)(ws + 9437184ull);       // 3,145,728
  ushort* wckv = (ushort*)(ws + 12582912ull);     // 6,291,456
  ushort* w1t = (ushort*)(ws + 18874368ull);      // 12,582,912
  ushort* w2t = (ushort*)(ws + 31457280ull);      // 12,582,912
  ushort* encb = (ushort*)(ws + 44040192ull);     // 4,194,304
  ushort* xb = (ushort*)(ws + 48234496ull);       // 4,194,304
  ushort* tmpb = (ushort*)(ws + 52428800ull);     // 4,194,304 (attn out)
  float* tmpf = (float*)(ws + 56623104ull);       // 16,777,216 (FF2 partials)
  ushort* qkvbuf = (ushort*)(ws + 73400320ull);   // [4096][1536] = 12,582,912
  ushort* cq = (ushort*)(ws + 73400320ull);       // time-shared
  ushort* ff1b = (ushort*)(ws + 73400320ull);     // time-shared
  ushort* vt = (ushort*)(ws + 85983232ull);       // 4,194,304
  float* qkvbias = (float*)(ws + 90177536ull);
  float* ckvbias = (float*)(ws + 90214400ull);
  ushort* ckvbuf = (ushort*)(ws + 90238976ull);   // [4096][6144] = 50,331,648
  ushort* vtc = (ushort*)(ws + 140570624ull);     // [6][8][8][64][512]

  const int M = BB * SS;  // 4096
  dim3 g256(256);

  embed_pe_kernel<<<dim3((M * DDIM + 255) / 256), g256, 0, stream>>>(dec, emb,
                                                                     xb);
  cast_bf16_kernel<<<dim3(M * DDIM / 4 / 256), g256, 0, stream>>>(
      enc, encb, M * DDIM / 4);
  pack_bias_kernel<<<dim3(36), g256, 0, stream>>>(bq_s, bk_s, bv_s, bk_c, bv_c,
                                                  qkvbias, ckvbias);

  wtrans_kernel<<<dim3(2, 16, 48), g256, 0, stream>>>(Wq_s, wqkv, 512, 64, 3,
                                                      786432ull);
  wtrans_kernel<<<dim3(2, 16, 48), g256, 0, stream>>>(Wk_s, wqkv + 262144, 512,
                                                      64, 3, 786432ull);
  wtrans_kernel<<<dim3(2, 16, 48), g256, 0, stream>>>(Wv_s, wqkv + 524288, 512,
                                                      64, 3, 786432ull);
  wtrans_kernel<<<dim3(2, 16, 48), g256, 0, stream>>>(Wq_c, wqc, 512, 64, 3,
                                                      262144ull);
  wtrans_kernel<<<dim3(2, 16, 48), g256, 0, stream>>>(Wk_c, wckv, 512, 64, 3,
                                                      524288ull);
  wtrans_kernel<<<dim3(2, 16, 48), g256, 0, stream>>>(Wv_c, wckv + 262144, 512,
                                                      64, 3, 524288ull);
  wtrans_kernel<<<dim3(64, 16, 6), g256, 0, stream>>>(W1, w1t, 512, 2048, 0,
                                                      1048576ull);
  wtrans_kernel<<<dim3(16, 64, 6), g256, 0, stream>>>(W2, w2t, 2048, 512, 0,
                                                      1048576ull);

  // ---- hoisted cross K/V for ALL layers (depends only on enc) ----
  gemm_mfma<128, 128, 0, 1, 512, 10, 1><<<dim3(48, 32), g256, 0, stream>>>(
      encb, wckv, ckvbias, nullptr, ckvbuf, vtc, M, 6144, 512);

  for (int l = 0; l < NLAYER; l++) {
    // ---- self attention: fused QKV GEMM (V transposed to vt) ----
    gemm_mfma<128, 128, 0, 1, 1024, 0, 1><<<dim3(12, 32), g256, 0, stream>>>(
        xb, wqkv + (size_t)l * 786432, qkvbias + l * 1536, nullptr, qkvbuf, vt,
        M, 1536, 512);
    attn_mfma<1><<<dim3(8, 8, 8), g256, 0, stream>>>(
        qkvbuf, 1536, qkvbuf + 512, 1536, vt, tmpb);
    add_ln_kernel<0><<<dim3(M / 4), g256, 0, stream>>>(
        xb, tmpb, nullptr, nullptr, ln1_g + l * 512, ln1_b + l * 512, nullptr);
    // ---- cross attention (K/V precomputed) ----
    gemm_mfma<64, 64, 0, 1, 0, 0, 1><<<dim3(8, 64), g256, 0, stream>>>(
        xb, wqc + (size_t)l * 262144, bq_c + l * 512, nullptr, cq, nullptr, M,
        512, 512);
    attn_mfma<0><<<dim3(8, 8, 8), g256, 0, stream>>>(
        cq, 512, ckvbuf + l * 1024, 6144, vtc + (size_t)l * 2097152, tmpb);
    add_ln_kernel<0><<<dim3(M / 4), g256, 0, stream>>>(
        xb, tmpb, nullptr, nullptr, ln2_g + l * 512, ln2_b + l * 512, nullptr);
    // ---- feed forward ----
    gemm_mfma<128, 128, 1, 1, 0, 0, 1><<<dim3(16, 32), g256, 0, stream>>>(
        xb, w1t + (size_t)l * 1048576, b1 + l * DFFV, nullptr, ff1b, nullptr,
        M, DFFV, 512);
    gemm_mfma<128, 64, 0, 0, 0, 0, 2><<<dim3(8, 32, 2), g256, 0, stream>>>(
        ff1b, w2t + (size_t)l * 1048576, b2 + l * 512, tmpf, nullptr, nullptr,
        M, 512, DFFV);
    add_ln_kernel<1><<<dim3(M / 4), g256, 0, stream>>>(
        xb, nullptr, tmpf, tmpf + (size_t)M * 512, ln2_g + l * 512,
        ln2_b + l * 512, (l == NLAYER - 1) ? (float*)d_out : nullptr);
  }
}

// Round 7
// 733.090 us; speedup vs baseline: 8.5061x; 1.0200x over previous
//
#include <hip/hip_runtime.h>
#include <hip/hip_bf16.h>
#include <math.h>

#define BB 8
#define SS 512
#define DDIM 512
#define HH 8
#define DFFV 2048
#define NLAYER 6
#define EPSV 1e-5f

typedef __attribute__((ext_vector_type(8))) short bf16x8;
typedef __attribute__((ext_vector_type(4))) float f32x4;

static __device__ __forceinline__ ushort f2bf(float f) {
  union { float f; unsigned u; } uf; uf.f = f;
  unsigned u = uf.u;
  unsigned r = (u + 0x7fffu + ((u >> 16) & 1u)) >> 16;
  return (ushort)r;
}
static __device__ __forceinline__ float bf2f(ushort h) {
  union { unsigned u; float f; } x;
  x.u = ((unsigned)h) << 16;
  return x.f;
}

static __device__ __forceinline__ void gload_lds16(const void* g, void* l) {
  __builtin_amdgcn_global_load_lds(
      (const __attribute__((address_space(1))) void*)g,
      (__attribute__((address_space(3))) void*)l, 16, 0, 0);
}

// ---------------- embed + positional encoding (bf16 xb) ----------
__global__ __launch_bounds__(256) void embed_pe_kernel(
    const int* __restrict__ idx, const float* __restrict__ emb,
    ushort* __restrict__ xb) {
  int t = blockIdx.x * blockDim.x + threadIdx.x;
  if (t >= BB * SS * DDIM) return;
  int d = t & (DDIM - 1);
  int bs = t >> 9;
  int s = bs & (SS - 1);
  int tok = idx[bs];
  int i2 = d & ~1;
  float ang = (float)s * powf(10000.0f, -((float)i2) / (float)DDIM);
  float pe = (d & 1) ? cosf(ang) : sinf(ang);
  float v = emb[tok * DDIM + d] + pe;
  xb[t] = f2bf(v);
}

// ---------------- fp32 -> bf16 cast ----------------
__global__ __launch_bounds__(256) void cast_bf16_kernel(
    const float* __restrict__ in, ushort* __restrict__ out, int n4) {
  int t = blockIdx.x * blockDim.x + threadIdx.x;
  if (t >= n4) return;
  float4 v = reinterpret_cast<const float4*>(in)[t];
  ushort4 o;
  o.x = f2bf(v.x); o.y = f2bf(v.y); o.z = f2bf(v.z); o.w = f2bf(v.w);
  reinterpret_cast<ushort4*>(out)[t] = o;
}

// ---------------- transpose-convert weights: [R][C] fp32 -> [C][R] bf16 ----
__global__ __launch_bounds__(256) void wtrans_kernel(
    const float* __restrict__ in, ushort* __restrict__ out, int R, int C,
    int lgH, size_t zl) {
  __shared__ float t[32][33];
  int z = blockIdx.z;
  int l = z >> lgH, hh = z & ((1 << lgH) - 1);
  const float* ip = in + (size_t)z * R * C;
  ushort* op = out + (size_t)l * zl + (size_t)hh * R * C;
  int j = threadIdx.x & 31, i0 = threadIdx.x >> 5;
  int r0 = blockIdx.y * 32, c0 = blockIdx.x * 32;
#pragma unroll
  for (int p = 0; p < 4; p++) {
    int r = r0 + i0 + p * 8;
    t[i0 + p * 8][j] = ip[(size_t)r * C + c0 + j];
  }
  __syncthreads();
#pragma unroll
  for (int p = 0; p < 4; p++) {
    int cc = c0 + i0 + p * 8;
    op[(size_t)cc * R + r0 + j] = f2bf(t[j][i0 + p * 8]);
  }
}

// ---------------- bias packing ----------------
__global__ __launch_bounds__(256) void pack_bias_kernel(
    const float* __restrict__ bq, const float* __restrict__ bk,
    const float* __restrict__ bv, const float* __restrict__ bkc,
    const float* __restrict__ bvc, float* __restrict__ qkvb,
    float* __restrict__ ckvb) {
  int t = blockIdx.x * 256 + threadIdx.x;
  if (t < NLAYER * 1536) {
    int l = t / 1536, n = t % 1536;
    float v = n < 512 ? bq[l * 512 + n]
                      : (n < 1024 ? bk[l * 512 + n - 512] : bv[l * 512 + n - 1024]);
    qkvb[t] = v;
  }
  if (t < NLAYER * 1024) {
    int l = t / 1024, n = t % 1024;
    ckvb[t] = n < 512 ? bkc[l * 512 + n] : bvc[l * 512 + n - 512];
  }
}

// ---------------- bf16 MFMA GEMM, 2-phase pipelined (counted vmcnt) -------
// A:[M][K] bf16, Bw:[N][K] bf16, bias fp32[N]. Tile BMxBN, BK=64, 4 waves.
// LDS double-buffered; XOR-swizzle via pre-swizzled global source.
// SPLITK>1: blockIdx.z picks K-chunk, fp32 partial to Cf + z*M*N (bias z==0).
// NTV>0: cols with (cc = LGP? col&((1<<LGP)-1) : col) >= NTV are written
// transposed to vt[lp][b][h][dv][s], lp = LGP? col>>LGP : 0.
template <int BM, int BN, int RELU, int OUTBF, int NTV, int LGP, int SPLITK>
__global__ __launch_bounds__(256) void gemm_mfma(
    const ushort* __restrict__ A, const ushort* __restrict__ Bw,
    const float* __restrict__ bias, float* __restrict__ Cf,
    ushort* __restrict__ Cb, ushort* __restrict__ vt, int M, int N, int K) {
  constexpr int WM = BM / 64;   // waves along M
  constexpr int WN = 4 / WM;    // waves along N
  constexpr int W = BN / WN;    // wave tile width
  constexpr int AF = 4;         // A fragments per wave (64 rows)
  constexpr int BF = W / 16;    // B fragments per wave
  constexpr int GA = BM * 8;    // A granules (16B) per K-step
  constexpr int GPT = (BM + BN) * 8 / 256;  // gload instrs/thread/stage
  __shared__ __align__(16) ushort lds_s[2][(BM + BN) * 64];
  int bn = blockIdx.x * BN, bm = blockIdx.y * BM;
  int kz = (SPLITK > 1) ? blockIdx.z : 0;
  int Keff = K / SPLITK;
  int kbase = kz * Keff;
  int tid = threadIdx.x, lane = tid & 63, w = tid >> 6;
  int wm = w / WN, wn = w % WN;
  int c = lane & 15, g16 = lane >> 4;
  f32x4 acc[AF][BF] = {};

  auto STAGE = [&](int k0, int bufi) {
#pragma unroll
    for (int i = 0; i < GPT; i++) {
      int gidx = i * 256 + tid;
      int gbase = (i * 4 + w) * 64;  // wave-uniform LDS granule base
      const ushort* src;
      if (gidx < GA) {
        int row = gidx >> 3, dg = gidx & 7;
        src = A + (size_t)(bm + row) * K + kbase + k0 + ((dg ^ (row & 7)) << 3);
      } else {
        int bidx = gidx - GA;
        int row = bidx >> 3, dg = bidx & 7;
        src = Bw + (size_t)(bn + row) * K + kbase + k0 + ((dg ^ (row & 7)) << 3);
      }
      gload_lds16(src, (void*)((char*)(&lds_s[bufi][0]) + gbase * 16));
    }
  };

  int nk = Keff >> 6;
  STAGE(0, 0);
  for (int kt = 0; kt < nk; kt++) {
    int cur = kt & 1;
    if (kt + 1 < nk) {
      STAGE((kt + 1) << 6, cur ^ 1);
      asm volatile("s_waitcnt vmcnt(%0)" ::"n"(GPT) : "memory");
    } else {
      asm volatile("s_waitcnt vmcnt(0)" ::: "memory");
    }
    __builtin_amdgcn_s_barrier();
    __builtin_amdgcn_sched_barrier(0);
    const ushort* Alds = &lds_s[cur][0];
    const ushort* Blds = &lds_s[cur][BM * 64];
#pragma unroll
    for (int ks = 0; ks < 2; ks++) {
      int g = ks * 4 + g16;
      bf16x8 a[AF], b[BF];
#pragma unroll
      for (int i = 0; i < AF; i++) {
        int R = wm * 64 + i * 16 + c;
        a[i] = *(const bf16x8*)(Alds + R * 64 + ((g ^ (R & 7)) << 3));
      }
#pragma unroll
      for (int j = 0; j < BF; j++) {
        int Rb = wn * W + j * 16 + c;
        b[j] = *(const bf16x8*)(Blds + Rb * 64 + ((g ^ (Rb & 7)) << 3));
      }
#pragma unroll
      for (int i = 0; i < AF; i++)
#pragma unroll
        for (int j = 0; j < BF; j++)
          acc[i][j] = __builtin_amdgcn_mfma_f32_16x16x32_bf16(a[i], b[j],
                                                              acc[i][j], 0, 0, 0);
    }
    __builtin_amdgcn_sched_barrier(0);
    __builtin_amdgcn_s_barrier();
  }
  int rb = g16 * 4;
#pragma unroll
  for (int j = 0; j < BF; j++) {
    int col = bn + wn * W + j * 16 + c;
    float bv = (SPLITK > 1 && kz != 0) ? 0.0f : bias[col];
    int cc = LGP ? (col & ((1 << LGP) - 1)) : col;
    int lp = LGP ? (col >> LGP) : 0;
    if (NTV > 0 && cc >= NTV) {
      int hh = (cc - NTV) >> 6, dv = col & 63;
      ushort* vtl = vt + (size_t)lp * 2097152;
#pragma unroll
      for (int i = 0; i < AF; i++) {
        int row = bm + wm * 64 + i * 16 + rb;
        int b_ = row >> 9, s_ = row & 511;
        ushort4 o4;
        o4.x = f2bf(acc[i][j][0] + bv);
        o4.y = f2bf(acc[i][j][1] + bv);
        o4.z = f2bf(acc[i][j][2] + bv);
        o4.w = f2bf(acc[i][j][3] + bv);
        *reinterpret_cast<ushort4*>(
            vtl + ((size_t)(b_ * 8 + hh) * 64 + dv) * 512 + s_) = o4;
      }
    } else {
#pragma unroll
      for (int i = 0; i < AF; i++) {
#pragma unroll
        for (int qq = 0; qq < 4; qq++) {
          int row = bm + wm * 64 + i * 16 + rb + qq;
          float v = acc[i][j][qq] + bv;
          if (RELU) v = fmaxf(v, 0.0f);
          if (OUTBF)
            Cb[(size_t)row * N + col] = f2bf(v);
          else
            Cf[(size_t)kz * M * N + (size_t)row * N + col] = v;
        }
      }
    }
  }
}

// ---------------- MFMA flash attention (dbuf K/V, 1 barrier/tile) ---------
// NW waves, QBLK = NW*16 q-rows per block. q: bf16 rows stride qstr (col off
// h*64); k same with kstr; vt: bf16 [b][h][64][512]; out bf16 [4096][512].
// MASKED=1: causal (mask synthesized inline). MASKED=0: no mask.
template <int MASKED, int NW>
__global__ __launch_bounds__(NW * 64) void attn_mfma(
    const ushort* __restrict__ q, int qstr, const ushort* __restrict__ k,
    int kstr, const ushort* __restrict__ vt, ushort* __restrict__ out) {
  // K0 @0 (8KB), V0 @8192, K1 @16384, V1 @24576, P @32768 (NW*2KB)
  __shared__ __align__(16) char lds[32768 + NW * 2048];
  int q0 = blockIdx.x * (NW * 16), h = blockIdx.y, b = blockIdx.z;
  int tid = threadIdx.x, lane = tid & 63, w = tid >> 6;
  int c = lane & 15, g16 = lane >> 4, rb = g16 * 4;

  bf16x8 qa[2];
#pragma unroll
  for (int ks = 0; ks < 2; ks++)
    qa[ks] = *(const bf16x8*)(q + (size_t)(b * SS + q0 + 16 * w + c) * qstr +
                              h * 64 + ks * 32 + g16 * 8);
  f32x4 o[4] = {};
  float mrow[4], lrow[4];
#pragma unroll
  for (int j = 0; j < 4; j++) { mrow[j] = -1e30f; lrow[j] = 0.f; }

  int nt = MASKED ? (q0 >> 6) + 1 : 8;
  int pbase = 32768 + w * 2048;

  constexpr int GPTK = 512 / (NW * 64);  // K (and V) granules per thread
  bf16x8 rk[GPTK], rv[GPTK];
  const ushort* vbase = vt + ((size_t)(b * 8 + h) * 64) * 512;
  auto LOADT = [&](int kv0) {
#pragma unroll
    for (int i = 0; i < GPTK; i++) {
      int idx = tid + i * (NW * 64);
      int row = idx >> 3, gw = idx & 7;
      rk[i] = *(const bf16x8*)(k + (size_t)(b * SS + kv0 + row) * kstr +
                               h * 64 + gw * 8);
      rv[i] = *(const bf16x8*)(vbase + (size_t)row * 512 + kv0 + gw * 8);
    }
  };
  auto WRT = [&](int bufi) {
    char* p = lds + bufi * 16384;
#pragma unroll
    for (int i = 0; i < GPTK; i++) {
      int idx = tid + i * (NW * 64);
      int row = idx >> 3, gw = idx & 7;
      *(bf16x8*)(p + row * 128 + ((gw ^ (row & 7)) << 4)) = rk[i];
      *(bf16x8*)(p + 8192 + row * 128 + ((gw ^ (row & 7)) << 4)) = rv[i];
    }
  };
  LOADT(0);
  WRT(0);
  for (int t = 0; t < nt; t++) {
    if (t + 1 < nt) LOADT((t + 1) * 64);
    __syncthreads();
    char* kb_ = lds + (t & 1) * 16384;
    char* vb_ = kb_ + 8192;
    // S = Q K^T
    f32x4 s[4] = {};
    __builtin_amdgcn_s_setprio(1);
#pragma unroll
    for (int ks = 0; ks < 2; ks++) {
      int g = ks * 4 + g16;
#pragma unroll
      for (int f = 0; f < 4; f++) {
        int row = f * 16 + c;
        bf16x8 k8 = *(bf16x8*)(kb_ + row * 128 + ((g ^ (row & 7)) << 4));
        s[f] = __builtin_amdgcn_mfma_f32_16x16x32_bf16(qa[ks], k8, s[f], 0, 0, 0);
      }
    }
    __builtin_amdgcn_s_setprio(0);
    if (MASKED && t == nt - 1) {
#pragma unroll
      for (int f = 0; f < 4; f++)
#pragma unroll
        for (int j = 0; j < 4; j++)
          s[f][j] = s[f][j] * 0.125f +
                    ((f * 16 + c) <= (16 * w + rb + j) ? 0.0f : -1e9f);
    } else {
#pragma unroll
      for (int f = 0; f < 4; f++)
#pragma unroll
        for (int j = 0; j < 4; j++) s[f][j] *= 0.125f;
    }
    // online softmax (rows in 16-lane groups)
#pragma unroll
    for (int j = 0; j < 4; j++) {
      float tm = fmaxf(fmaxf(s[0][j], s[1][j]), fmaxf(s[2][j], s[3][j]));
      tm = fmaxf(tm, __shfl_xor(tm, 1));
      tm = fmaxf(tm, __shfl_xor(tm, 2));
      tm = fmaxf(tm, __shfl_xor(tm, 4));
      tm = fmaxf(tm, __shfl_xor(tm, 8));
      float mn = fmaxf(mrow[j], tm);
      float sc = __expf(mrow[j] - mn);
      float p0 = __expf(s[0][j] - mn), p1 = __expf(s[1][j] - mn);
      float p2 = __expf(s[2][j] - mn), p3 = __expf(s[3][j] - mn);
      s[0][j] = p0; s[1][j] = p1; s[2][j] = p2; s[3][j] = p3;
      float ps = p0 + p1 + p2 + p3;
      ps += __shfl_xor(ps, 1);
      ps += __shfl_xor(ps, 2);
      ps += __shfl_xor(ps, 4);
      ps += __shfl_xor(ps, 8);
      lrow[j] = lrow[j] * sc + ps;
      mrow[j] = mn;
      o[0][j] *= sc; o[1][j] *= sc; o[2][j] *= sc; o[3][j] *= sc;
    }
    // P (C-layout) -> per-wave LDS bf16 [16 q rows][64 kv]
#pragma unroll
    for (int f = 0; f < 4; f++) {
      int col = f * 16 + c;
      int cg = col >> 3, cb2 = (col & 7) * 2;
#pragma unroll
      for (int j = 0; j < 4; j++) {
        int r = rb + j;
        *(ushort*)(lds + pbase + r * 128 + ((cg ^ (r & 7)) << 4) + cb2) =
            f2bf(s[f][j]);
      }
    }
    // O += P V
    __builtin_amdgcn_s_setprio(1);
#pragma unroll
    for (int ks2 = 0; ks2 < 2; ks2++) {
      int g = ks2 * 4 + g16;
      bf16x8 pa = *(bf16x8*)(lds + pbase + c * 128 + ((g ^ (c & 7)) << 4));
#pragma unroll
      for (int f = 0; f < 4; f++) {
        int row = f * 16 + c;
        bf16x8 v8 = *(bf16x8*)(vb_ + row * 128 + ((g ^ (row & 7)) << 4));
        o[f] = __builtin_amdgcn_mfma_f32_16x16x32_bf16(pa, v8, o[f], 0, 0, 0);
      }
    }
    __builtin_amdgcn_s_setprio(0);
    if (t + 1 < nt) WRT((t + 1) & 1);
  }
#pragma unroll
  for (int j = 0; j < 4; j++) {
    float inv = 1.0f / lrow[j];
    size_t rowo = (size_t)(b * SS + q0 + 16 * w + rb + j) * 512 + h * 64;
#pragma unroll
    for (int f = 0; f < 4; f++)
      out[rowo + f * 16 + c] = f2bf(o[f][j] * inv);
  }
}

// ---------------- residual add + LayerNorm (bf16 residual, wave/row) ------
// Y2=0: y = bf16 yb.  Y2=1: y = fp32 y0 + fp32 y1 (split-K partials).
// Writes xb (bf16); if xf != nullptr also writes fp32.
template <int Y2>
__global__ __launch_bounds__(256) void add_ln_kernel(
    ushort* __restrict__ xb, const ushort* __restrict__ yb,
    const float* __restrict__ y0, const float* __restrict__ y1,
    const float* __restrict__ g, const float* __restrict__ bta,
    float* __restrict__ xf) {
  int row = blockIdx.x * 4 + (threadIdx.x >> 6);
  int lane = threadIdx.x & 63;
  int base = row * DDIM + lane * 8;
  bf16x8 xv = *reinterpret_cast<const bf16x8*>(xb + base);
  float v[8];
  if (Y2) {
    float4 a0 = *reinterpret_cast<const float4*>(y0 + base);
    float4 a1 = *reinterpret_cast<const float4*>(y0 + base + 4);
    float4 c0 = *reinterpret_cast<const float4*>(y1 + base);
    float4 c1 = *reinterpret_cast<const float4*>(y1 + base + 4);
    v[0] = bf2f((ushort)xv[0]) + a0.x + c0.x;
    v[1] = bf2f((ushort)xv[1]) + a0.y + c0.y;
    v[2] = bf2f((ushort)xv[2]) + a0.z + c0.z;
    v[3] = bf2f((ushort)xv[3]) + a0.w + c0.w;
    v[4] = bf2f((ushort)xv[4]) + a1.x + c1.x;
    v[5] = bf2f((ushort)xv[5]) + a1.y + c1.y;
    v[6] = bf2f((ushort)xv[6]) + a1.z + c1.z;
    v[7] = bf2f((ushort)xv[7]) + a1.w + c1.w;
  } else {
    bf16x8 yv = *reinterpret_cast<const bf16x8*>(yb + base);
#pragma unroll
    for (int i = 0; i < 8; i++)
      v[i] = bf2f((ushort)xv[i]) + bf2f((ushort)yv[i]);
  }
  float s = 0.f;
#pragma unroll
  for (int i = 0; i < 8; i++) s += v[i];
#pragma unroll
  for (int off = 32; off > 0; off >>= 1) s += __shfl_xor(s, off);
  float mean = s * (1.0f / DDIM);
  float t2 = 0.f;
#pragma unroll
  for (int i = 0; i < 8; i++) {
    v[i] -= mean;
    t2 += v[i] * v[i];
  }
#pragma unroll
  for (int off = 32; off > 0; off >>= 1) t2 += __shfl_xor(t2, off);
  float rs = rsqrtf(t2 * (1.0f / DDIM) + EPSV);
  int cidx = lane * 8;
  float4 g0 = *reinterpret_cast<const float4*>(g + cidx);
  float4 g1 = *reinterpret_cast<const float4*>(g + cidx + 4);
  float4 b0 = *reinterpret_cast<const float4*>(bta + cidx);
  float4 b1 = *reinterpret_cast<const float4*>(bta + cidx + 4);
  float o[8];
  o[0] = v[0] * rs * g0.x + b0.x; o[1] = v[1] * rs * g0.y + b0.y;
  o[2] = v[2] * rs * g0.z + b0.z; o[3] = v[3] * rs * g0.w + b0.w;
  o[4] = v[4] * rs * g1.x + b1.x; o[5] = v[5] * rs * g1.y + b1.y;
  o[6] = v[6] * rs * g1.z + b1.z; o[7] = v[7] * rs * g1.w + b1.w;
  bf16x8 ob;
#pragma unroll
  for (int i = 0; i < 8; i++) ob[i] = (short)f2bf(o[i]);
  *reinterpret_cast<bf16x8*>(xb + base) = ob;
  if (xf) {
    float4 w0 = {o[0], o[1], o[2], o[3]}, w1 = {o[4], o[5], o[6], o[7]};
    *reinterpret_cast<float4*>(xf + base) = w0;
    *reinterpret_cast<float4*>(xf + base + 4) = w1;
  }
}

// ---------------- orchestration ----------------
extern "C" void kernel_launch(void* const* d_in, const int* in_sizes, int n_in,
                              void* d_out, int out_size, void* d_ws,
                              size_t ws_size, hipStream_t stream) {
  const int* dec = (const int*)d_in[0];
  const float* enc = (const float*)d_in[1];
  const float* emb = (const float*)d_in[4];
  const float* Wq_s = (const float*)d_in[5];
  const float* Wk_s = (const float*)d_in[6];
  const float* Wv_s = (const float*)d_in[7];
  const float* bq_s = (const float*)d_in[8];
  const float* bk_s = (const float*)d_in[9];
  const float* bv_s = (const float*)d_in[10];
  const float* Wq_c = (const float*)d_in[11];
  const float* Wk_c = (const float*)d_in[12];
  const float* Wv_c = (const float*)d_in[13];
  const float* bq_c = (const float*)d_in[14];
  const float* bk_c = (const float*)d_in[15];
  const float* bv_c = (const float*)d_in[16];
  const float* W1 = (const float*)d_in[17];
  const float* b1 = (const float*)d_in[18];
  const float* W2 = (const float*)d_in[19];
  const float* b2 = (const float*)d_in[20];
  const float* ln1_g = (const float*)d_in[21];
  const float* ln1_b = (const float*)d_in[22];
  const float* ln2_g = (const float*)d_in[23];
  const float* ln2_b = (const float*)d_in[24];

  char* ws = (char*)d_ws;
  ushort* wqkv = (ushort*)(ws + 0);               // 9,437,184
  ushort* wqc = (ushort*)(ws + 9437184ull);       // 3,145,728
  ushort* wckv = (ushort*)(ws + 12582912ull);     // 6,291,456
  ushort* w1t = (ushort*)(ws + 18874368ull);      // 12,582,912
  ushort* w2t = (ushort*)(ws + 31457280ull);      // 12,582,912
  ushort* encb = (ushort*)(ws + 44040192ull);     // 4,194,304
  ushort* xb = (ushort*)(ws + 48234496ull);       // 4,194,304
  ushort* tmpb = (ushort*)(ws + 52428800ull);     // 4,194,304 (attn out)
  float* tmpf = (float*)(ws + 56623104ull);       // 16,777,216 (FF2 partials)
  ushort* qkvbuf = (ushort*)(ws + 73400320ull);   // [4096][1536] = 12,582,912
  ushort* cq = (ushort*)(ws + 73400320ull);       // time-shared
  ushort* ff1b = (ushort*)(ws + 73400320ull);     // time-shared
  ushort* vt = (ushort*)(ws + 85983232ull);       // 4,194,304
  float* qkvbias = (float*)(ws + 90177536ull);
  float* ckvbias = (float*)(ws + 90214400ull);
  ushort* ckvbuf = (ushort*)(ws + 90238976ull);   // [4096][6144] = 50,331,648
  ushort* vtc = (ushort*)(ws + 140570624ull);     // [6][8][8][64][512]

  const int M = BB * SS;  // 4096
  dim3 g256(256);

  embed_pe_kernel<<<dim3((M * DDIM + 255) / 256), g256, 0, stream>>>(dec, emb,
                                                                     xb);
  cast_bf16_kernel<<<dim3(M * DDIM / 4 / 256), g256, 0, stream>>>(
      enc, encb, M * DDIM / 4);
  pack_bias_kernel<<<dim3(36), g256, 0, stream>>>(bq_s, bk_s, bv_s, bk_c, bv_c,
                                                  qkvbias, ckvbias);

  wtrans_kernel<<<dim3(2, 16, 48), g256, 0, stream>>>(Wq_s, wqkv, 512, 64, 3,
                                                      786432ull);
  wtrans_kernel<<<dim3(2, 16, 48), g256, 0, stream>>>(Wk_s, wqkv + 262144, 512,
                                                      64, 3, 786432ull);
  wtrans_kernel<<<dim3(2, 16, 48), g256, 0, stream>>>(Wv_s, wqkv + 524288, 512,
                                                      64, 3, 786432ull);
  wtrans_kernel<<<dim3(2, 16, 48), g256, 0, stream>>>(Wq_c, wqc, 512, 64, 3,
                                                      262144ull);
  wtrans_kernel<<<dim3(2, 16, 48), g256, 0, stream>>>(Wk_c, wckv, 512, 64, 3,
                                                      524288ull);
  wtrans_kernel<<<dim3(2, 16, 48), g256, 0, stream>>>(Wv_c, wckv + 262144, 512,
                                                      64, 3, 524288ull);
  wtrans_kernel<<<dim3(64, 16, 6), g256, 0, stream>>>(W1, w1t, 512, 2048, 0,
                                                      1048576ull);
  wtrans_kernel<<<dim3(16, 64, 6), g256, 0, stream>>>(W2, w2t, 2048, 512, 0,
                                                      1048576ull);

  // ---- hoisted cross K/V for ALL layers (depends only on enc) ----
  gemm_mfma<128, 128, 0, 1, 512, 10, 1><<<dim3(48, 32), g256, 0, stream>>>(
      encb, wckv, ckvbias, nullptr, ckvbuf, vtc, M, 6144, 512);

  for (int l = 0; l < NLAYER; l++) {
    // ---- self attention: fused QKV GEMM (V transposed to vt) ----
    gemm_mfma<64, 128, 0, 1, 1024, 0, 1><<<dim3(12, 64), g256, 0, stream>>>(
        xb, wqkv + (size_t)l * 786432, qkvbias + l * 1536, nullptr, qkvbuf, vt,
        M, 1536, 512);
    attn_mfma<1, 4><<<dim3(8, 8, 8), g256, 0, stream>>>(
        qkvbuf, 1536, qkvbuf + 512, 1536, vt, tmpb);
    add_ln_kernel<0><<<dim3(M / 4), g256, 0, stream>>>(
        xb, tmpb, nullptr, nullptr, ln1_g + l * 512, ln1_b + l * 512, nullptr);
    // ---- cross attention (K/V precomputed); 8-wave QBLK=128 ----
    gemm_mfma<64, 64, 0, 1, 0, 0, 1><<<dim3(8, 64), g256, 0, stream>>>(
        xb, wqc + (size_t)l * 262144, bq_c + l * 512, nullptr, cq, nullptr, M,
        512, 512);
    attn_mfma<0, 8><<<dim3(4, 8, 8), dim3(512), 0, stream>>>(
        cq, 512, ckvbuf + l * 1024, 6144, vtc + (size_t)l * 2097152, tmpb);
    add_ln_kernel<0><<<dim3(M / 4), g256, 0, stream>>>(
        xb, tmpb, nullptr, nullptr, ln2_g + l * 512, ln2_b + l * 512, nullptr);
    // ---- feed forward ----
    gemm_mfma<128, 128, 1, 1, 0, 0, 1><<<dim3(16, 32), g256, 0, stream>>>(
        xb, w1t + (size_t)l * 1048576, b1 + l * DFFV, nullptr, ff1b, nullptr,
        M, DFFV, 512);
    gemm_mfma<128, 64, 0, 0, 0, 0, 2><<<dim3(8, 32, 2), g256, 0, stream>>>(
        ff1b, w2t + (size_t)l * 1048576, b2 + l * 512, tmpf, nullptr, nullptr,
        M, 512, DFFV);
    add_ln_kernel<1><<<dim3(M / 4), g256, 0, stream>>>(
        xb, nullptr, tmpf, tmpf + (size_t)M * 512, ln2_g + l * 512,
        ln2_b + l * 512, (l == NLAYER - 1) ? (float*)d_out : nullptr);
  }
}

// Round 8
// 643.594 us; speedup vs baseline: 9.6889x; 1.1391x over previous
//
#include <hip/hip_runtime.h>
#include <hip/hip_bf16.h>
#include <math.h>

#define BB 8
#define SS 512
#define DDIM 512
#define HH 8
#define DFFV 2048
#define NLAYER 6
#define EPSV 1e-5f
#define WQS 0.180336880f  // 0.125 * log2(e)

typedef __attribute__((ext_vector_type(8))) short bf16x8;
typedef __attribute__((ext_vector_type(4))) float f32x4;

static __device__ __forceinline__ ushort f2bf(float f) {
  union { float f; unsigned u; } uf; uf.f = f;
  unsigned u = uf.u;
  unsigned r = (u + 0x7fffu + ((u >> 16) & 1u)) >> 16;
  return (ushort)r;
}
static __device__ __forceinline__ float bf2f(ushort h) {
  union { unsigned u; float f; } x;
  x.u = ((unsigned)h) << 16;
  return x.f;
}

static __device__ __forceinline__ void gload_lds16(const void* g, void* l) {
  __builtin_amdgcn_global_load_lds(
      (const __attribute__((address_space(1))) void*)g,
      (__attribute__((address_space(3))) void*)l, 16, 0, 0);
}

// ---------------- embed + positional encoding (bf16 xb) ----------
__global__ __launch_bounds__(256) void embed_pe_kernel(
    const int* __restrict__ idx, const float* __restrict__ emb,
    ushort* __restrict__ xb) {
  int t = blockIdx.x * blockDim.x + threadIdx.x;
  if (t >= BB * SS * DDIM) return;
  int d = t & (DDIM - 1);
  int bs = t >> 9;
  int s = bs & (SS - 1);
  int tok = idx[bs];
  int i2 = d & ~1;
  float ang = (float)s * powf(10000.0f, -((float)i2) / (float)DDIM);
  float pe = (d & 1) ? cosf(ang) : sinf(ang);
  float v = emb[tok * DDIM + d] + pe;
  xb[t] = f2bf(v);
}

// ---------------- fp32 -> bf16 cast ----------------
__global__ __launch_bounds__(256) void cast_bf16_kernel(
    const float* __restrict__ in, ushort* __restrict__ out, int n4) {
  int t = blockIdx.x * blockDim.x + threadIdx.x;
  if (t >= n4) return;
  float4 v = reinterpret_cast<const float4*>(in)[t];
  ushort4 o;
  o.x = f2bf(v.x); o.y = f2bf(v.y); o.z = f2bf(v.z); o.w = f2bf(v.w);
  reinterpret_cast<ushort4*>(out)[t] = o;
}

// ---------------- transpose-convert weights: [R][C] fp32 -> [C][R] bf16 ----
__global__ __launch_bounds__(256) void wtrans_kernel(
    const float* __restrict__ in, ushort* __restrict__ out, int R, int C,
    int lgH, size_t zl, float scale) {
  __shared__ float t[32][33];
  int z = blockIdx.z;
  int l = z >> lgH, hh = z & ((1 << lgH) - 1);
  const float* ip = in + (size_t)z * R * C;
  ushort* op = out + (size_t)l * zl + (size_t)hh * R * C;
  int j = threadIdx.x & 31, i0 = threadIdx.x >> 5;
  int r0 = blockIdx.y * 32, c0 = blockIdx.x * 32;
#pragma unroll
  for (int p = 0; p < 4; p++) {
    int r = r0 + i0 + p * 8;
    t[i0 + p * 8][j] = ip[(size_t)r * C + c0 + j];
  }
  __syncthreads();
#pragma unroll
  for (int p = 0; p < 4; p++) {
    int cc = c0 + i0 + p * 8;
    op[(size_t)cc * R + r0 + j] = f2bf(t[j][i0 + p * 8] * scale);
  }
}

// ---------------- bias packing ----------------
__global__ __launch_bounds__(256) void pack_bias_kernel(
    const float* __restrict__ bq, const float* __restrict__ bk,
    const float* __restrict__ bv, const float* __restrict__ bkc,
    const float* __restrict__ bvc, const float* __restrict__ bqc,
    float* __restrict__ qkvb, float* __restrict__ ckvb,
    float* __restrict__ cqb) {
  int t = blockIdx.x * 256 + threadIdx.x;
  if (t < NLAYER * 1536) {
    int l = t / 1536, n = t % 1536;
    float v = n < 512 ? bq[l * 512 + n] * WQS
                      : (n < 1024 ? bk[l * 512 + n - 512] : bv[l * 512 + n - 1024]);
    qkvb[t] = v;
  }
  if (t < NLAYER * 1024) {
    int l = t / 1024, n = t % 1024;
    ckvb[t] = n < 512 ? bkc[l * 512 + n] : bvc[l * 512 + n - 512];
  }
  if (t < NLAYER * 512) cqb[t] = bqc[t] * WQS;
}

// ---------------- bf16 MFMA GEMM, 2-phase pipelined (counted vmcnt) -------
// A:[M][K] bf16, Bw:[N][K] bf16, bias fp32[N]. Tile BMxBN, BK=64, 4 waves.
// XCD-aware block swizzle (grids divisible by 8). LDS double-buffered;
// XOR-swizzle via pre-swizzled global source.
// SPLITK>1: blockIdx.z picks K-chunk, fp32 partial to Cf + z*M*N (bias z==0).
// NTV>0: cols with (cc = LGP? col&((1<<LGP)-1) : col) >= NTV are written
// transposed to vt[lp][b][h][dv][s], lp = LGP? col>>LGP : 0.
template <int BM, int BN, int RELU, int OUTBF, int NTV, int LGP, int SPLITK>
__global__ __launch_bounds__(256) void gemm_mfma(
    const ushort* __restrict__ A, const ushort* __restrict__ Bw,
    const float* __restrict__ bias, float* __restrict__ Cf,
    ushort* __restrict__ Cb, ushort* __restrict__ vt, int M, int N, int K) {
  constexpr int WM = BM / 64;   // waves along M
  constexpr int WN = 4 / WM;    // waves along N
  constexpr int W = BN / WN;    // wave tile width
  constexpr int AF = 4;         // A fragments per wave (64 rows)
  constexpr int BF = W / 16;    // B fragments per wave
  constexpr int GA = BM * 8;    // A granules (16B) per K-step
  constexpr int GPT = (BM + BN) * 8 / 256;  // gload instrs/thread/stage
  __shared__ __align__(16) ushort lds_s[2][(BM + BN) * 64];
  // XCD-aware bijective swizzle (nwg % 8 == 0 for all our grids)
  int nwg = gridDim.x * gridDim.y;
  int wg = blockIdx.y * gridDim.x + blockIdx.x;
  int cpx = nwg >> 3;
  int swz = (wg & 7) * cpx + (wg >> 3);
  int bn = (swz % gridDim.x) * BN, bm = (swz / gridDim.x) * BM;
  int kz = (SPLITK > 1) ? blockIdx.z : 0;
  int Keff = K / SPLITK;
  int kbase = kz * Keff;
  int tid = threadIdx.x, lane = tid & 63, w = tid >> 6;
  int wm = w / WN, wn = w % WN;
  int c = lane & 15, g16 = lane >> 4;
  f32x4 acc[AF][BF] = {};

  auto STAGE = [&](int k0, int bufi) {
#pragma unroll
    for (int i = 0; i < GPT; i++) {
      int gidx = i * 256 + tid;
      int gbase = (i * 4 + w) * 64;  // wave-uniform LDS granule base
      const ushort* src;
      if (gidx < GA) {
        int row = gidx >> 3, dg = gidx & 7;
        src = A + (size_t)(bm + row) * K + kbase + k0 + ((dg ^ (row & 7)) << 3);
      } else {
        int bidx = gidx - GA;
        int row = bidx >> 3, dg = bidx & 7;
        src = Bw + (size_t)(bn + row) * K + kbase + k0 + ((dg ^ (row & 7)) << 3);
      }
      gload_lds16(src, (void*)((char*)(&lds_s[bufi][0]) + gbase * 16));
    }
  };

  int nk = Keff >> 6;
  STAGE(0, 0);
  for (int kt = 0; kt < nk; kt++) {
    int cur = kt & 1;
    if (kt + 1 < nk) {
      STAGE((kt + 1) << 6, cur ^ 1);
      asm volatile("s_waitcnt vmcnt(%0)" ::"n"(GPT) : "memory");
    } else {
      asm volatile("s_waitcnt vmcnt(0)" ::: "memory");
    }
    __builtin_amdgcn_s_barrier();
    __builtin_amdgcn_sched_barrier(0);
    const ushort* Alds = &lds_s[cur][0];
    const ushort* Blds = &lds_s[cur][BM * 64];
#pragma unroll
    for (int ks = 0; ks < 2; ks++) {
      int g = ks * 4 + g16;
      bf16x8 a[AF], b[BF];
#pragma unroll
      for (int i = 0; i < AF; i++) {
        int R = wm * 64 + i * 16 + c;
        a[i] = *(const bf16x8*)(Alds + R * 64 + ((g ^ (R & 7)) << 3));
      }
#pragma unroll
      for (int j = 0; j < BF; j++) {
        int Rb = wn * W + j * 16 + c;
        b[j] = *(const bf16x8*)(Blds + Rb * 64 + ((g ^ (Rb & 7)) << 3));
      }
#pragma unroll
      for (int i = 0; i < AF; i++)
#pragma unroll
        for (int j = 0; j < BF; j++)
          acc[i][j] = __builtin_amdgcn_mfma_f32_16x16x32_bf16(a[i], b[j],
                                                              acc[i][j], 0, 0, 0);
    }
    __builtin_amdgcn_sched_barrier(0);
    __builtin_amdgcn_s_barrier();
  }
  int rb = g16 * 4;
#pragma unroll
  for (int j = 0; j < BF; j++) {
    int col = bn + wn * W + j * 16 + c;
    float bv = (SPLITK > 1 && kz != 0) ? 0.0f : bias[col];
    int cc = LGP ? (col & ((1 << LGP) - 1)) : col;
    int lp = LGP ? (col >> LGP) : 0;
    if (NTV > 0 && cc >= NTV) {
      int hh = (cc - NTV) >> 6, dv = col & 63;
      ushort* vtl = vt + (size_t)lp * 2097152;
#pragma unroll
      for (int i = 0; i < AF; i++) {
        int row = bm + wm * 64 + i * 16 + rb;
        int b_ = row >> 9, s_ = row & 511;
        ushort4 o4;
        o4.x = f2bf(acc[i][j][0] + bv);
        o4.y = f2bf(acc[i][j][1] + bv);
        o4.z = f2bf(acc[i][j][2] + bv);
        o4.w = f2bf(acc[i][j][3] + bv);
        *reinterpret_cast<ushort4*>(
            vtl + ((size_t)(b_ * 8 + hh) * 64 + dv) * 512 + s_) = o4;
      }
    } else {
#pragma unroll
      for (int i = 0; i < AF; i++) {
#pragma unroll
        for (int qq = 0; qq < 4; qq++) {
          int row = bm + wm * 64 + i * 16 + rb + qq;
          float v = acc[i][j][qq] + bv;
          if (RELU) v = fmaxf(v, 0.0f);
          if (OUTBF)
            Cb[(size_t)row * N + col] = f2bf(v);
          else
            Cf[(size_t)kz * M * N + (size_t)row * N + col] = v;
        }
      }
    }
  }
}

// ---------------- MFMA flash attention (swapped QK^T, lane-local softmax) --
// Q is pre-scaled by 0.125*log2e (scores in log2-domain; exp2f softmax).
// NW waves, QBLK = NW*16 q-rows per block. q: bf16 rows stride qstr (col off
// h*64); k same with kstr; vt: bf16 [b][h][64][512]; out bf16 [4096][512].
// MASKED=1: causal (mask synthesized inline). MASKED=0: no mask.
template <int MASKED, int NW>
__global__ __launch_bounds__(NW * 64) void attn_mfma(
    const ushort* __restrict__ q, int qstr, const ushort* __restrict__ k,
    int kstr, const ushort* __restrict__ vt, ushort* __restrict__ out) {
  // K0 @0 (8KB), V0 @8192, K1 @16384, V1 @24576, P @32768 (NW*2KB)
  __shared__ __align__(16) char lds[32768 + NW * 2048];
  int q0 = blockIdx.x * (NW * 16), h = blockIdx.y, b = blockIdx.z;
  int tid = threadIdx.x, lane = tid & 63, w = tid >> 6;
  int c = lane & 15, g16 = lane >> 4, rb = g16 * 4;

  bf16x8 qa[2];
#pragma unroll
  for (int ks = 0; ks < 2; ks++)
    qa[ks] = *(const bf16x8*)(q + (size_t)(b * SS + q0 + 16 * w + c) * qstr +
                              h * 64 + ks * 32 + g16 * 8);
  f32x4 o[4] = {};
  float mq = -1e30f, lq = 0.f;  // per-lane state for q = c

  int nt = MASKED ? (q0 >> 6) + 1 : 8;
  int pbase = 32768 + w * 2048;

  constexpr int GPTK = 512 / (NW * 64);  // K (and V) granules per thread
  bf16x8 rk[GPTK], rv[GPTK];
  const ushort* vbase = vt + ((size_t)(b * 8 + h) * 64) * 512;
  auto LOADT = [&](int kv0) {
#pragma unroll
    for (int i = 0; i < GPTK; i++) {
      int idx = tid + i * (NW * 64);
      int row = idx >> 3, gw = idx & 7;
      rk[i] = *(const bf16x8*)(k + (size_t)(b * SS + kv0 + row) * kstr +
                               h * 64 + gw * 8);
      rv[i] = *(const bf16x8*)(vbase + (size_t)row * 512 + kv0 + gw * 8);
    }
  };
  auto WRT = [&](int bufi) {
    char* p = lds + bufi * 16384;
#pragma unroll
    for (int i = 0; i < GPTK; i++) {
      int idx = tid + i * (NW * 64);
      int row = idx >> 3, gw = idx & 7;
      *(bf16x8*)(p + row * 128 + ((gw ^ (row & 7)) << 4)) = rk[i];
      *(bf16x8*)(p + 8192 + row * 128 + ((gw ^ (row & 7)) << 4)) = rv[i];
    }
  };
  LOADT(0);
  WRT(0);
  for (int t = 0; t < nt; t++) {
    if (t + 1 < nt) LOADT((t + 1) * 64);
    __syncthreads();
    char* kb_ = lds + (t & 1) * 16384;
    char* vb_ = kb_ + 8192;
    // S' = K Q^T : sp[f][j] = S[kv = f*16 + rb + j][q = c]  (log2-domain)
    f32x4 sp[4] = {};
    __builtin_amdgcn_s_setprio(1);
#pragma unroll
    for (int ks = 0; ks < 2; ks++) {
      int g = ks * 4 + g16;
#pragma unroll
      for (int f = 0; f < 4; f++) {
        int row = f * 16 + c;
        bf16x8 k8 = *(bf16x8*)(kb_ + row * 128 + ((g ^ (row & 7)) << 4));
        sp[f] = __builtin_amdgcn_mfma_f32_16x16x32_bf16(k8, qa[ks], sp[f], 0, 0, 0);
      }
    }
    __builtin_amdgcn_s_setprio(0);
    if (MASKED && t == nt - 1) {
      int ql = 16 * w + c;
#pragma unroll
      for (int f = 0; f < 4; f++)
#pragma unroll
        for (int j = 0; j < 4; j++)
          sp[f][j] += (f * 16 + rb + j) <= ql ? 0.0f : -1e9f;
    }
    // lane-local softmax for q = c (reduce over kv: in-reg + g16 lanes)
    float tmax = -1e30f;
#pragma unroll
    for (int f = 0; f < 4; f++)
#pragma unroll
      for (int j = 0; j < 4; j++) tmax = fmaxf(tmax, sp[f][j]);
    tmax = fmaxf(tmax, __shfl_xor(tmax, 16));
    tmax = fmaxf(tmax, __shfl_xor(tmax, 32));
    float mn = fmaxf(mq, tmax);
    float scq = exp2f(mq - mn);
    float psum = 0.f;
#pragma unroll
    for (int f = 0; f < 4; f++)
#pragma unroll
      for (int j = 0; j < 4; j++) {
        float pv = exp2f(sp[f][j] - mn);
        sp[f][j] = pv;
        psum += pv;
      }
    psum += __shfl_xor(psum, 16);
    psum += __shfl_xor(psum, 32);
    lq = lq * scq + psum;
    mq = mn;
    // rescale O (o's q-row = rb + j; fetch sc from lane c' = rb + j)
    int sb = lane & 48;
#pragma unroll
    for (int j = 0; j < 4; j++) {
      float scj = __shfl(scq, sb | (rb + j));
      o[0][j] *= scj; o[1][j] *= scj; o[2][j] *= scj; o[3][j] *= scj;
    }
    // P store: lane holds P[q=c][kv = f*16+rb+{0..3}] -> 4x ds_write_b64
#pragma unroll
    for (int f = 0; f < 4; f++) {
      int kv0 = f * 16 + rb;
      ushort4 pk;
      pk.x = f2bf(sp[f][0]); pk.y = f2bf(sp[f][1]);
      pk.z = f2bf(sp[f][2]); pk.w = f2bf(sp[f][3]);
      int gg = kv0 >> 3, off = (kv0 & 7) * 2;
      *(ushort4*)(lds + pbase + c * 128 + (((gg) ^ (c & 7)) << 4) + off) = pk;
    }
    // O += P V
    __builtin_amdgcn_s_setprio(1);
#pragma unroll
    for (int ks2 = 0; ks2 < 2; ks2++) {
      int g = ks2 * 4 + g16;
      bf16x8 pa = *(bf16x8*)(lds + pbase + c * 128 + ((g ^ (c & 7)) << 4));
#pragma unroll
      for (int f = 0; f < 4; f++) {
        int row = f * 16 + c;
        bf16x8 v8 = *(bf16x8*)(vb_ + row * 128 + ((g ^ (row & 7)) << 4));
        o[f] = __builtin_amdgcn_mfma_f32_16x16x32_bf16(pa, v8, o[f], 0, 0, 0);
      }
    }
    __builtin_amdgcn_s_setprio(0);
    if (t + 1 < nt) WRT((t + 1) & 1);
  }
  float invq = 1.0f / lq;
  int sb = lane & 48;
#pragma unroll
  for (int j = 0; j < 4; j++) {
    float invj = __shfl(invq, sb | (rb + j));
    size_t rowo = (size_t)(b * SS + q0 + 16 * w + rb + j) * 512 + h * 64;
#pragma unroll
    for (int f = 0; f < 4; f++)
      out[rowo + f * 16 + c] = f2bf(o[f][j] * invj);
  }
}

// ---------------- residual add + LayerNorm (bf16 residual, wave/row) ------
// Y2=0: y = bf16 yb.  Y2=1: y = fp32 y0 + fp32 y1 (split-K partials).
// Writes xb (bf16); if xf != nullptr also writes fp32.
template <int Y2>
__global__ __launch_bounds__(256) void add_ln_kernel(
    ushort* __restrict__ xb, const ushort* __restrict__ yb,
    const float* __restrict__ y0, const float* __restrict__ y1,
    const float* __restrict__ g, const float* __restrict__ bta,
    float* __restrict__ xf) {
  int row = blockIdx.x * 4 + (threadIdx.x >> 6);
  int lane = threadIdx.x & 63;
  int base = row * DDIM + lane * 8;
  bf16x8 xv = *reinterpret_cast<const bf16x8*>(xb + base);
  float v[8];
  if (Y2) {
    float4 a0 = *reinterpret_cast<const float4*>(y0 + base);
    float4 a1 = *reinterpret_cast<const float4*>(y0 + base + 4);
    float4 c0 = *reinterpret_cast<const float4*>(y1 + base);
    float4 c1 = *reinterpret_cast<const float4*>(y1 + base + 4);
    v[0] = bf2f((ushort)xv[0]) + a0.x + c0.x;
    v[1] = bf2f((ushort)xv[1]) + a0.y + c0.y;
    v[2] = bf2f((ushort)xv[2]) + a0.z + c0.z;
    v[3] = bf2f((ushort)xv[3]) + a0.w + c0.w;
    v[4] = bf2f((ushort)xv[4]) + a1.x + c1.x;
    v[5] = bf2f((ushort)xv[5]) + a1.y + c1.y;
    v[6] = bf2f((ushort)xv[6]) + a1.z + c1.z;
    v[7] = bf2f((ushort)xv[7]) + a1.w + c1.w;
  } else {
    bf16x8 yv = *reinterpret_cast<const bf16x8*>(yb + base);
#pragma unroll
    for (int i = 0; i < 8; i++)
      v[i] = bf2f((ushort)xv[i]) + bf2f((ushort)yv[i]);
  }
  float s = 0.f;
#pragma unroll
  for (int i = 0; i < 8; i++) s += v[i];
#pragma unroll
  for (int off = 32; off > 0; off >>= 1) s += __shfl_xor(s, off);
  float mean = s * (1.0f / DDIM);
  float t2 = 0.f;
#pragma unroll
  for (int i = 0; i < 8; i++) {
    v[i] -= mean;
    t2 += v[i] * v[i];
  }
#pragma unroll
  for (int off = 32; off > 0; off >>= 1) t2 += __shfl_xor(t2, off);
  float rs = rsqrtf(t2 * (1.0f / DDIM) + EPSV);
  int cidx = lane * 8;
  float4 g0 = *reinterpret_cast<const float4*>(g + cidx);
  float4 g1 = *reinterpret_cast<const float4*>(g + cidx + 4);
  float4 b0 = *reinterpret_cast<const float4*>(bta + cidx);
  float4 b1 = *reinterpret_cast<const float4*>(bta + cidx + 4);
  float o[8];
  o[0] = v[0] * rs * g0.x + b0.x; o[1] = v[1] * rs * g0.y + b0.y;
  o[2] = v[2] * rs * g0.z + b0.z; o[3] = v[3] * rs * g0.w + b0.w;
  o[4] = v[4] * rs * g1.x + b1.x; o[5] = v[5] * rs * g1.y + b1.y;
  o[6] = v[6] * rs * g1.z + b1.z; o[7] = v[7] * rs * g1.w + b1.w;
  bf16x8 ob;
#pragma unroll
  for (int i = 0; i < 8; i++) ob[i] = (short)f2bf(o[i]);
  *reinterpret_cast<bf16x8*>(xb + base) = ob;
  if (xf) {
    float4 w0 = {o[0], o[1], o[2], o[3]}, w1 = {o[4], o[5], o[6], o[7]};
    *reinterpret_cast<float4*>(xf + base) = w0;
    *reinterpret_cast<float4*>(xf + base + 4) = w1;
  }
}

// ---------------- orchestration ----------------
extern "C" void kernel_launch(void* const* d_in, const int* in_sizes, int n_in,
                              void* d_out, int out_size, void* d_ws,
                              size_t ws_size, hipStream_t stream) {
  const int* dec = (const int*)d_in[0];
  const float* enc = (const float*)d_in[1];
  const float* emb = (const float*)d_in[4];
  const float* Wq_s = (const float*)d_in[5];
  const float* Wk_s = (const float*)d_in[6];
  const float* Wv_s = (const float*)d_in[7];
  const float* bq_s = (const float*)d_in[8];
  const float* bk_s = (const float*)d_in[9];
  const float* bv_s = (const float*)d_in[10];
  const float* Wq_c = (const float*)d_in[11];
  const float* Wk_c = (const float*)d_in[12];
  const float* Wv_c = (const float*)d_in[13];
  const float* bq_c = (const float*)d_in[14];
  const float* bk_c = (const float*)d_in[15];
  const float* bv_c = (const float*)d_in[16];
  const float* W1 = (const float*)d_in[17];
  const float* b1 = (const float*)d_in[18];
  const float* W2 = (const float*)d_in[19];
  const float* b2 = (const float*)d_in[20];
  const float* ln1_g = (const float*)d_in[21];
  const float* ln1_b = (const float*)d_in[22];
  const float* ln2_g = (const float*)d_in[23];
  const float* ln2_b = (const float*)d_in[24];

  char* ws = (char*)d_ws;
  ushort* wqkv = (ushort*)(ws + 0);               // 9,437,184
  ushort* wqc = (ushort*)(ws + 9437184ull);       // 3,145,728
  ushort* wckv = (ushort*)(ws + 12582912ull);     // 6,291,456
  ushort* w1t = (ushort*)(ws + 18874368ull);      // 12,582,912
  ushort* w2t = (ushort*)(ws + 31457280ull);      // 12,582,912
  ushort* encb = (ushort*)(ws + 44040192ull);     // 4,194,304
  ushort* xb = (ushort*)(ws + 48234496ull);       // 4,194,304
  ushort* tmpb = (ushort*)(ws + 52428800ull);     // 4,194,304 (attn out)
  float* tmpf = (float*)(ws + 56623104ull);       // 16,777,216 (FF2 partials)
  ushort* qkvbuf = (ushort*)(ws + 73400320ull);   // [4096][1536] = 12,582,912
  ushort* cq = (ushort*)(ws + 73400320ull);       // time-shared
  ushort* ff1b = (ushort*)(ws + 73400320ull);     // time-shared
  ushort* vt = (ushort*)(ws + 85983232ull);       // 4,194,304
  float* qkvbias = (float*)(ws + 90177536ull);
  float* ckvbias = (float*)(ws + 90214400ull);
  ushort* ckvbuf = (ushort*)(ws + 90238976ull);   // [4096][6144] = 50,331,648
  ushort* vtc = (ushort*)(ws + 140570624ull);     // [6][8][8][64][512]
  float* cqbias = (float*)(ws + 165736448ull);    // 6*512*4

  const int M = BB * SS;  // 4096
  dim3 g256(256);

  embed_pe_kernel<<<dim3((M * DDIM + 255) / 256), g256, 0, stream>>>(dec, emb,
                                                                     xb);
  cast_bf16_kernel<<<dim3(M * DDIM / 4 / 256), g256, 0, stream>>>(
      enc, encb, M * DDIM / 4);
  pack_bias_kernel<<<dim3(36), g256, 0, stream>>>(bq_s, bk_s, bv_s, bk_c, bv_c,
                                                  bq_c, qkvbias, ckvbias,
                                                  cqbias);

  wtrans_kernel<<<dim3(2, 16, 48), g256, 0, stream>>>(Wq_s, wqkv, 512, 64, 3,
                                                      786432ull, WQS);
  wtrans_kernel<<<dim3(2, 16, 48), g256, 0, stream>>>(Wk_s, wqkv + 262144, 512,
                                                      64, 3, 786432ull, 1.0f);
  wtrans_kernel<<<dim3(2, 16, 48), g256, 0, stream>>>(Wv_s, wqkv + 524288, 512,
                                                      64, 3, 786432ull, 1.0f);
  wtrans_kernel<<<dim3(2, 16, 48), g256, 0, stream>>>(Wq_c, wqc, 512, 64, 3,
                                                      262144ull, WQS);
  wtrans_kernel<<<dim3(2, 16, 48), g256, 0, stream>>>(Wk_c, wckv, 512, 64, 3,
                                                      524288ull, 1.0f);
  wtrans_kernel<<<dim3(2, 16, 48), g256, 0, stream>>>(Wv_c, wckv + 262144, 512,
                                                      64, 3, 524288ull, 1.0f);
  wtrans_kernel<<<dim3(64, 16, 6), g256, 0, stream>>>(W1, w1t, 512, 2048, 0,
                                                      1048576ull, 1.0f);
  wtrans_kernel<<<dim3(16, 64, 6), g256, 0, stream>>>(W2, w2t, 2048, 512, 0,
                                                      1048576ull, 1.0f);

  // ---- hoisted cross K/V for ALL layers (depends only on enc) ----
  gemm_mfma<128, 128, 0, 1, 512, 10, 1><<<dim3(48, 32), g256, 0, stream>>>(
      encb, wckv, ckvbias, nullptr, ckvbuf, vtc, M, 6144, 512);

  for (int l = 0; l < NLAYER; l++) {
    // ---- self attention: fused QKV GEMM (V transposed to vt) ----
    gemm_mfma<64, 128, 0, 1, 1024, 0, 1><<<dim3(12, 64), g256, 0, stream>>>(
        xb, wqkv + (size_t)l * 786432, qkvbias + l * 1536, nullptr, qkvbuf, vt,
        M, 1536, 512);
    attn_mfma<1, 4><<<dim3(8, 8, 8), g256, 0, stream>>>(
        qkvbuf, 1536, qkvbuf + 512, 1536, vt, tmpb);
    add_ln_kernel<0><<<dim3(M / 4), g256, 0, stream>>>(
        xb, tmpb, nullptr, nullptr, ln1_g + l * 512, ln1_b + l * 512, nullptr);
    // ---- cross attention (K/V precomputed); 8-wave QBLK=128 ----
    gemm_mfma<64, 64, 0, 1, 0, 0, 1><<<dim3(8, 64), g256, 0, stream>>>(
        xb, wqc + (size_t)l * 262144, cqbias + l * 512, nullptr, cq, nullptr,
        M, 512, 512);
    attn_mfma<0, 8><<<dim3(4, 8, 8), dim3(512), 0, stream>>>(
        cq, 512, ckvbuf + l * 1024, 6144, vtc + (size_t)l * 2097152, tmpb);
    add_ln_kernel<0><<<dim3(M / 4), g256, 0, stream>>>(
        xb, tmpb, nullptr, nullptr, ln2_g + l * 512, ln2_b + l * 512, nullptr);
    // ---- feed forward ----
    gemm_mfma<128, 128, 1, 1, 0, 0, 1><<<dim3(16, 32), g256, 0, stream>>>(
        xb, w1t + (size_t)l * 1048576, b1 + l * DFFV, nullptr, ff1b, nullptr,
        M, DFFV, 512);
    gemm_mfma<128, 64, 0, 0, 0, 0, 2><<<dim3(8, 32, 2), g256, 0, stream>>>(
        ff1b, w2t + (size_t)l * 1048576, b2 + l * 512, tmpf, nullptr, nullptr,
        M, 512, DFFV);
    add_ln_kernel<1><<<dim3(M / 4), g256, 0, stream>>>(
        xb, nullptr, tmpf, tmpf + (size_t)M * 512, ln2_g + l * 512,
        ln2_b + l * 512, (l == NLAYER - 1) ? (float*)d_out : nullptr);
  }
}